// Round 3
// baseline (575.771 us; speedup 1.0000x reference)
//
#include <hip/hip_runtime.h>
#include <stdint.h>

// ---------------- common helpers ----------------

using f32x4 = __attribute__((ext_vector_type(4))) float;
using s16x8 = __attribute__((ext_vector_type(8))) short;

__device__ __forceinline__ ushort f2b(float f) {
    union { float f; uint32_t u; } v; v.f = f;
    uint32_t u = v.u;
    return (ushort)((u + 0x7fffu + ((u >> 16) & 1u)) >> 16);
}
__device__ __forceinline__ float b2f(ushort b) {
    union { uint32_t u; float f; } v; v.u = ((uint32_t)b) << 16;
    return v.f;
}
__device__ __forceinline__ float to_f(float f) { return f; }
__device__ __forceinline__ float to_f(ushort b) { return b2f(b); }

// async global->LDS, 16B per lane; LDS dest = wave-uniform base + lane*16
__device__ __forceinline__ void async_ld16(const ushort* g, ushort* l) {
    __builtin_amdgcn_global_load_lds(
        (const __attribute__((address_space(1))) void*)g,
        (__attribute__((address_space(3))) void*)l,
        16, 0, 0);
}

// s_waitcnt immediates (gfx9): vmcnt[3:0]|[15:14], expcnt[6:4], lgkmcnt[11:8]
#define WAITCNT_VM4    0x0F74  // vmcnt=4, lgkm/exp no-wait
#define WAITCNT_VM0    0x0F70  // vmcnt=0
#define WAITCNT_LGKM12 0xCC7F  // lgkmcnt=12, vmcnt/exp no-wait
#define WAITCNT_LGKM0  0xC07F  // lgkmcnt=0

// ---------------- cast fp32 -> bf16 (vectorized x4) ----------------

__global__ __launch_bounds__(256) void cast_f2b4(const float* __restrict__ src,
                                                 ushort* __restrict__ dst,
                                                 long long n4) {
    long long i = (long long)blockIdx.x * 256 + threadIdx.x;
    if (i >= n4) return;
    float4 f = ((const float4*)src)[i];
    ushort4 o;
    o.x = f2b(f.x); o.y = f2b(f.y); o.z = f2b(f.z); o.w = f2b(f.w);
    ((ushort4*)dst)[i] = o;
}

// ---------------- bias concat: [bq|bk|bv] -> dst (3*1024 floats) ----------------

__global__ __launch_bounds__(256) void concat3(const float* __restrict__ a,
                                               const float* __restrict__ b,
                                               const float* __restrict__ c,
                                               float* __restrict__ dst) {
    int i = blockIdx.x * 256 + threadIdx.x;  // grid 12 blocks = 3072
    const float* s = (i < 1024) ? a : (i < 2048) ? b : c;
    dst[i] = s[i & 1023];
}

// ---------------- split-K partial reduce + cast to bf16 --------------------------

__global__ __launch_bounds__(256) void add2_cast(const float* __restrict__ a,
                                                 const float* __restrict__ b,
                                                 ushort* __restrict__ o,
                                                 long long n4) {
    long long i = (long long)blockIdx.x * 256 + threadIdx.x;
    if (i >= n4) return;
    float4 x = ((const float4*)a)[i];
    float4 y = ((const float4*)b)[i];
    ushort4 u;
    u.x = f2b(x.x + y.x); u.y = f2b(x.y + y.y);
    u.z = f2b(x.z + y.z); u.w = f2b(x.w + y.w);
    ((ushort4*)o)[i] = u;
}

// ---------------- transpose (fp32 or bf16 in) -> bf16 out ----------------
// src: [R][C] with row stride srcLd, dst: [C][R] row-major.
// Grid: (C/32, R/32, batch), block (32,8).

template <typename T>
__global__ __launch_bounds__(256) void transpose_to_bf16(const T* __restrict__ src,
                                                         ushort* __restrict__ dst,
                                                         int R, int C, int srcLd,
                                                         long long ss, long long ds) {
    __shared__ float tile[32][33];
    src += (long long)blockIdx.z * ss;
    dst += (long long)blockIdx.z * ds;
    const int c0 = blockIdx.x * 32;
    const int r0 = blockIdx.y * 32;
    const int tx = threadIdx.x, ty = threadIdx.y;
#pragma unroll
    for (int i = 0; i < 4; i++) {
        int r = r0 + ty + i * 8;
        tile[ty + i * 8][tx] = to_f(src[(long long)r * srcLd + c0 + tx]);
    }
    __syncthreads();
#pragma unroll
    for (int i = 0; i < 4; i++) {
        int r = c0 + ty + i * 8;  // row of dst, in [0, C)
        dst[(long long)r * R + r0 + tx] = f2b(tile[tx][ty + i * 8]);
    }
}

// ---- fused 4x (1024x1024) transpose-cast: z selects {wq,wk,wv,wo}, dst contiguous ----

__global__ __launch_bounds__(256) void transpose4_to_bf16(const float* __restrict__ s0,
                                                          const float* __restrict__ s1,
                                                          const float* __restrict__ s2,
                                                          const float* __restrict__ s3,
                                                          ushort* __restrict__ dst) {
    __shared__ float tile[32][33];
    const int D = 1024;
    const int z = blockIdx.z;
    const float* src = (z == 0) ? s0 : (z == 1) ? s1 : (z == 2) ? s2 : s3;
    dst += (long long)z * D * D;
    const int c0 = blockIdx.x * 32;
    const int r0 = blockIdx.y * 32;
    const int tx = threadIdx.x, ty = threadIdx.y;
#pragma unroll
    for (int i = 0; i < 4; i++) {
        int r = r0 + ty + i * 8;
        tile[ty + i * 8][tx] = src[(long long)r * D + c0 + tx];
    }
    __syncthreads();
#pragma unroll
    for (int i = 0; i < 4; i++) {
        int r = c0 + ty + i * 8;
        dst[(long long)r * D + r0 + tx] = f2b(tile[tx][ty + i * 8]);
    }
}

// ---------------- bf16 MFMA GEMM, 256x256 tile, 4-buffer BK=32 pipeline ----------
// C[M,N] = A[M,K] * BT[N,K]^T (+bias, relu, scale). 512 threads = 8 waves (2M x 4N),
// per-wave 128x64 output = acc[8][4] f32x4.
//
// R3 restructure (R2 post-mortem: 6360 cyc/K-tile vs 2483 MFMA floor; frag ds_reads
// were lockstep-serialized between barriers, 8 barriers/tile). Now: BK=32, FOUR
// 32 KB LDS buffers (A[4][256][32] + B[4][256][32] = 128 KB), ONE barrier per
// K-tile, fragments register-prefetched one tile ahead, counted waits only:
//   iter t: issue 12 ds_reads frags(t+1) [buf published last iter]
//           issue 4 global_load_lds staging(t+3) -> buf (t+3)&3
//           lgkmcnt(12)  [frags(t) arrived; frags(t+1) stay in flight]
//           32 MFMA on frags(t)          <- reads/staging overlap this block
//           vmcnt(4) [staging(t+2) done; (t+3) in flight]; s_barrier [publish t+2]
// Buffer-reuse safety: staging(x+3) targets buf (x-1)&3; all reads of tile x-1
// were lgkm-retired before barrier(x-1), and max wave skew is one barrier.
// At 64 B rows the b128 frag-read pattern is naturally bank-balanced -> NO swizzle;
// staging is plain contiguous (lane -> row lane>>2, col (lane&3)*8).
// Epilogue: R2's LDS-staged coalesced C-write (verified: WRITE_SIZE == logical).
// Split-K (kChunks>1): chunk kIdx writes partials at C + kIdx*sK; bias chunk 0 only.

template <int OUT_BF16, int RELU, int HAS_BIAS>
__global__ __launch_bounds__(512, 2) void gemm256(const ushort* __restrict__ A,
                                                  const ushort* __restrict__ BT,
                                                  void* __restrict__ Cp,
                                                  const float* __restrict__ bias,
                                                  int K, int kChunks, float scale,
                                                  int lda, int ldb, int ldc,
                                                  long long sA, long long sB,
                                                  long long sC, long long sK) {
    __shared__ ushort SH[65536];   // 128 KB: A bufs [4][256][32] @0, B bufs @+32768 elems
    ushort* Asl = SH;
    ushort* Bsl = SH + 32768;

    const int tid = threadIdx.x;
    const int kIdx = blockIdx.z % kChunks;
    const int bz = blockIdx.z / kChunks;
    const int kLen = K / kChunks;
    const int kOff = kIdx * kLen;
    const int kTiles = kLen >> 5;   // BK=32
    const ushort* Ab = A + (long long)bz * sA;
    const ushort* Bb = BT + (long long)bz * sB;

    // XCD-panel swizzle (T1; bijective since gridDim.y % 8 == 0 for all our grids)
    const int W = gridDim.x, H = gridDim.y;
    const int bidx = blockIdx.y * W + blockIdx.x;
    const int Hp = H >> 3;
    const int xcd = bidx & 7;
    const int sb = bidx >> 3;
    const int tn = sb / Hp;
    const int tm = xcd * Hp + sb % Hp;

    const int lane = tid & 63;
    const int w = tid >> 6;    // wave 0..7
    const int wm = w >> 2;     // M half 0..1
    const int wn = w & 3;      // N quarter 0..3
    const int l16 = lane & 15;
    const int quad = lane >> 4;

    // ---- staging: per tile A = 16 KB = 16 x 1KB instr (2/wave), B same.
    // instr covers 16 rows x 32 cols; lane l -> row + (l>>2), col (l&3)*8. Linear.
    const int lr = lane >> 2;        // 0..15
    const int lc = (lane & 3) * 8;   // 0/8/16/24
    const ushort* AgS = Ab + (long long)(tm * 256 + w * 32 + lr) * lda + kOff + lc;
    const ushort* BgS = Bb + (long long)(tn * 256 + w * 32 + lr) * ldb + kOff + lc;
    ushort* AsW = Asl + w * 1024;    // wave's 32 rows within a buf
    ushort* BsW = Bsl + w * 1024;
    const long long rstepA = (long long)16 * lda;
    const long long rstepB = (long long)16 * ldb;

#define STG(tt) { const int bf_ = (tt) & 3;                                       \
        const ushort* ga_ = AgS + (tt) * 32; const ushort* gb_ = BgS + (tt) * 32; \
        async_ld16(ga_, AsW + bf_ * 8192);                                        \
        async_ld16(ga_ + rstepA, AsW + bf_ * 8192 + 512);                         \
        async_ld16(gb_, BsW + bf_ * 8192);                                        \
        async_ld16(gb_ + rstepB, BsW + bf_ * 8192 + 512); }

    // ---- fragment read bases (elem offsets into row-major [256][32] buf)
    const ushort* ArdB = Asl + (wm * 128 + l16) * 32 + quad * 8;  // + i*512 + bf*8192
    const ushort* BrdB = Bsl + (wn * 64 + l16) * 32 + quad * 8;   // + j*512 + bf*8192

#define LDF(pre, tt) { const int bf_ = (tt) & 3;                                  \
        const ushort* Ar_ = ArdB + bf_ * 8192;                                    \
        const ushort* Br_ = BrdB + bf_ * 8192;                                    \
        _Pragma("unroll") for (int i_ = 0; i_ < 8; i_++)                          \
            pre##a[i_] = *(const s16x8*)(Ar_ + i_ * 512);                         \
        _Pragma("unroll") for (int j_ = 0; j_ < 4; j_++)                          \
            pre##b[j_] = *(const s16x8*)(Br_ + j_ * 512); }

#define MM(pre) {                                                                 \
        __builtin_amdgcn_sched_barrier(0);                                        \
        __builtin_amdgcn_s_setprio(1);                                            \
        _Pragma("unroll") for (int i_ = 0; i_ < 8; i_++)                          \
            _Pragma("unroll") for (int j_ = 0; j_ < 4; j_++)                      \
                acc[i_][j_] = __builtin_amdgcn_mfma_f32_16x16x32_bf16(            \
                    pre##a[i_], pre##b[j_], acc[i_][j_], 0, 0, 0);                \
        __builtin_amdgcn_s_setprio(0);                                            \
        __builtin_amdgcn_sched_barrier(0); }

    f32x4 acc[8][4];
#pragma unroll
    for (int i = 0; i < 8; i++)
#pragma unroll
        for (int j = 0; j < 4; j++) acc[i][j] = (f32x4){0.f, 0.f, 0.f, 0.f};

    s16x8 fca[8], fna[8];
    s16x8 fcb[4], fnb[4];

    // ---- prologue: stage tiles 0,1,2; publish 0,1; prefetch frags(0)
    STG(0); STG(1); STG(2);
    __builtin_amdgcn_s_waitcnt(WAITCNT_VM4);   // tiles 0,1 landed; tile 2 in flight
    __builtin_amdgcn_s_barrier();              // publish 0,1
    LDF(fc, 0);

    for (int t = 0; t < kTiles; t += 2) {
        // ---- even iter: consume fc(t), prefetch fn(t+1)
        if (t + 1 < kTiles) LDF(fn, t + 1);
        if (t + 3 < kTiles) STG(t + 3);
        if (t + 1 < kTiles) __builtin_amdgcn_s_waitcnt(WAITCNT_LGKM12);
        else                __builtin_amdgcn_s_waitcnt(WAITCNT_LGKM0);
        MM(fc);
        if (t + 2 < kTiles) {
            if (t + 3 < kTiles) __builtin_amdgcn_s_waitcnt(WAITCNT_VM4);
            else                __builtin_amdgcn_s_waitcnt(WAITCNT_VM0);
            __builtin_amdgcn_s_barrier();      // publish t+2
        }
        // ---- odd iter: consume fn(t+1), prefetch fc(t+2)
        if (t + 1 < kTiles) {
            if (t + 2 < kTiles) LDF(fc, t + 2);
            if (t + 4 < kTiles) STG(t + 4);
            if (t + 2 < kTiles) __builtin_amdgcn_s_waitcnt(WAITCNT_LGKM12);
            else                __builtin_amdgcn_s_waitcnt(WAITCNT_LGKM0);
            MM(fn);
            if (t + 3 < kTiles) {
                if (t + 4 < kTiles) __builtin_amdgcn_s_waitcnt(WAITCNT_VM4);
                else                __builtin_amdgcn_s_waitcnt(WAITCNT_VM0);
                __builtin_amdgcn_s_barrier();  // publish t+3
            }
        }
    }
#undef STG
#undef LDF
#undef MM

    __builtin_amdgcn_s_barrier();  // all waves' frag reads retired before C-staging

    // ---- epilogue: acc C/D layout col = lane&15, row = quad*4 + reg [m89/m91].
    // Stage into LDS (group-XOR ^quad -> conflict-free writes; full-row reads),
    // then fully-coalesced global stores (R2-verified: WRITE_SIZE == logical).
    const long long cb = (long long)bz * sC + (long long)kIdx * sK;
    if (OUT_BF16) {
        ushort* Cb = (ushort*)Cp;
        // stage: SH as [256 rows][16 groups of 16 ushorts], group ^= quad
#pragma unroll
        for (int j = 0; j < 4; j++) {
            const int cg = wn * 4 + j;  // col group (col>>4), uniform per wave
            const float bv = HAS_BIAS ? bias[tn * 256 + cg * 16 + l16] : 0.0f;
#pragma unroll
            for (int i = 0; i < 8; i++) {
                const int rbase = wm * 128 + i * 16 + quad * 4;
#pragma unroll
                for (int r = 0; r < 4; r++) {
                    const int row = rbase + r;
                    float v = acc[i][j][r] * scale + bv;
                    if (RELU) v = v > 0.f ? v : 0.f;
                    SH[row * 256 + ((cg ^ ((row >> 2) & 3)) << 4) + l16] = f2b(v);
                }
            }
        }
        __builtin_amdgcn_s_barrier();
        // readout: 16 passes x (16 rows x 32 chunks of 16B); 512B contiguous/row
        const int crow = tid >> 5;  // 0..15
        const int cch = tid & 31;   // 0..31
        const int g = cch >> 1, hh = cch & 1;
#pragma unroll
        for (int pass = 0; pass < 16; pass++) {
            const int row = pass * 16 + crow;
            s16x8 vv = *(const s16x8*)&SH[row * 256 + ((g ^ ((row >> 2) & 3)) << 4) + hh * 8];
            *(s16x8*)&Cb[cb + (long long)(tm * 256 + row) * ldc + tn * 256 + cch * 8] = vv;
        }
    } else {
        float* Cf = (float*)Cp;
        float* SHf = (float*)SH;  // [128 rows][32 groups of 8 floats] per half-pass
#pragma unroll
        for (int half = 0; half < 2; half++) {
            if (wm == half) {
#pragma unroll
                for (int j = 0; j < 4; j++) {
                    const int col = wn * 64 + j * 16 + l16;
                    const float bv = (HAS_BIAS && kIdx == 0) ? bias[tn * 256 + col] : 0.0f;
                    const int gg = col >> 3, cl = col & 7;
#pragma unroll
                    for (int i = 0; i < 8; i++) {
                        const int rbase = i * 16 + quad * 4;  // row within half
#pragma unroll
                        for (int r = 0; r < 4; r++) {
                            const int row = rbase + r;
                            float v = acc[i][j][r] * scale + bv;
                            if (RELU) v = v > 0.f ? v : 0.f;
                            SHf[row * 256 + ((gg ^ ((row >> 2) & 3)) << 3) + cl] = v;
                        }
                    }
                }
            }
            __builtin_amdgcn_s_barrier();
            // readout: 16 passes x (8 rows x 64 chunks of 16B); 1024B contiguous/row
            const int rr = tid >> 6, cc = tid & 63;
            const int g2 = cc >> 1, h2 = cc & 1;
#pragma unroll
            for (int pass = 0; pass < 16; pass++) {
                const int row = pass * 8 + rr;
                f32x4 vv = *(const f32x4*)&SHf[row * 256 + ((g2 ^ ((row >> 2) & 3)) << 3) + h2 * 4];
                *(f32x4*)&Cf[cb + (long long)(tm * 256 + half * 128 + row) * ldc + tn * 256 + cc * 4] = vv;
            }
            __builtin_amdgcn_s_barrier();
        }
    }
}

// ---------------- row softmax: bf16 [rows][2048] -> bf16, vectorized 8/thread -------

__global__ __launch_bounds__(256) void softmax_rows(const ushort* __restrict__ S,
                                                    ushort* __restrict__ P) {
    const int C = 2048;
    const long long row = blockIdx.x;
    const int tid = threadIdx.x;
    const ushort4* s4 = (const ushort4*)(S + row * C) + tid * 2;  // 8 contiguous elems
    ushort4 a = s4[0], bq = s4[1];
    float v[8];
    v[0] = b2f(a.x); v[1] = b2f(a.y); v[2] = b2f(a.z); v[3] = b2f(a.w);
    v[4] = b2f(bq.x); v[5] = b2f(bq.y); v[6] = b2f(bq.z); v[7] = b2f(bq.w);
    float mx = -1e30f;
#pragma unroll
    for (int i = 0; i < 8; i++) mx = fmaxf(mx, v[i]);
    __shared__ float red[256];
    red[tid] = mx;
    __syncthreads();
    for (int off = 128; off > 0; off >>= 1) {
        if (tid < off) red[tid] = fmaxf(red[tid], red[tid + off]);
        __syncthreads();
    }
    mx = red[0];
    __syncthreads();
    float sum = 0.f;
#pragma unroll
    for (int i = 0; i < 8; i++) {
        v[i] = __expf(v[i] - mx);
        sum += v[i];
    }
    red[tid] = sum;
    __syncthreads();
    for (int off = 128; off > 0; off >>= 1) {
        if (tid < off) red[tid] += red[tid + off];
        __syncthreads();
    }
    float inv = 1.f / red[0];
    ushort4 o0, o1;
    o0.x = f2b(v[0] * inv); o0.y = f2b(v[1] * inv); o0.z = f2b(v[2] * inv); o0.w = f2b(v[3] * inv);
    o1.x = f2b(v[4] * inv); o1.y = f2b(v[5] * inv); o1.z = f2b(v[6] * inv); o1.w = f2b(v[7] * inv);
    ushort4* p4 = (ushort4*)(P + row * C) + tid * 2;
    p4[0] = o0;
    p4[1] = o1;
}

// ---------------- fused residual(+partial-sum) + LayerNorm (D=1024) ----------------
// out = LN(X + Y + (Y2?)) ; Y2 nullable (split-K partial reduction fused here).

__global__ __launch_bounds__(256) void residual_ln(const float* __restrict__ X,
                                                   const float* __restrict__ Y,
                                                   const float* __restrict__ Y2,
                                                   const float* __restrict__ g,
                                                   const float* __restrict__ be,
                                                   float* __restrict__ outf,
                                                   ushort* __restrict__ outb) {
    const int D = 1024;
    const long long row = blockIdx.x;
    const float* x = X + row * D;
    const float* y = Y + row * D;
    const float* y2 = Y2 ? Y2 + row * D : nullptr;
    const int tid = threadIdx.x;
    float v[4];
    float s = 0.f, s2 = 0.f;
#pragma unroll
    for (int i = 0; i < 4; i++) {
        int c = tid + i * 256;
        float t = x[c] + y[c];
        if (y2) t += y2[c];
        v[i] = t;
        s += t;
        s2 += t * t;
    }
    __shared__ float r1[256], r2[256];
    r1[tid] = s;
    r2[tid] = s2;
    __syncthreads();
    for (int off = 128; off > 0; off >>= 1) {
        if (tid < off) {
            r1[tid] += r1[tid + off];
            r2[tid] += r2[tid + off];
        }
        __syncthreads();
    }
    float mu = r1[0] * (1.f / 1024.f);
    float var = r2[0] * (1.f / 1024.f) - mu * mu;
    float inv = rsqrtf(var + 1e-5f);
    float* of = outf + row * D;
    ushort* ob = outb ? outb + row * D : nullptr;
#pragma unroll
    for (int i = 0; i < 4; i++) {
        int c = tid + i * 256;
        float o = (v[i] - mu) * inv * g[c] + be[c];
        of[c] = o;
        if (ob) ob[c] = f2b(o);
    }
}

// ---------------- launch ----------------

extern "C" void kernel_launch(void* const* d_in, const int* in_sizes, int n_in,
                              void* d_out, int out_size, void* d_ws, size_t ws_size,
                              hipStream_t stream) {
    const float* x  = (const float*)d_in[0];
    const float* wq = (const float*)d_in[1];
    const float* bq = (const float*)d_in[2];
    const float* wk = (const float*)d_in[3];
    const float* bk = (const float*)d_in[4];
    const float* wv = (const float*)d_in[5];
    const float* bv = (const float*)d_in[6];
    const float* wo = (const float*)d_in[7];
    const float* bo = (const float*)d_in[8];
    const float* w1 = (const float*)d_in[9];
    const float* b1 = (const float*)d_in[10];
    const float* w2 = (const float*)d_in[11];
    const float* b2 = (const float*)d_in[12];
    const float* g1 = (const float*)d_in[13];
    const float* be1 = (const float*)d_in[14];
    const float* g2 = (const float*)d_in[15];
    const float* be2 = (const float*)d_in[16];
    float* out = (float*)d_out;
    char* ws = (char*)d_ws;

    const int Bz = 4, S = 2048, D = 1024, F = 4096;
    const int T = Bz * S;  // 8192 rows
    const size_t MBy = 1024ull * 1024ull;

    // workspace layout (byte offsets), lifetime-based reuse; peak 201 MB
    ushort* qkvT = (ushort*)(ws + 0);        // 6 MB  [3072][1024]; woT follows contiguously
    ushort* woT  = (ushort*)(ws + 6 * MBy);  // 2 MB
    ushort* w1T  = (ushort*)(ws + 8 * MBy);  // 8 MB   [F][D]
    ushort* w2T  = (ushort*)(ws + 16 * MBy); // 8 MB   [D][F]
    float*  bqkv = (float*)(ws + 24 * MBy);  // 12 KB  (dead after QKV gemm)
    ushort* xb   = (ushort*)(ws + 25 * MBy); // 16 MB  (dead after QKV gemm)
    ushort* qkv  = (ushort*)(ws + 41 * MBy); // 48 MB  [T][3072] (dead after scores+vT)
    ushort* vT   = (ushort*)(ws + 89 * MBy); // 16 MB  [B][D][S] (dead after ctx)
    ushort* scb  = (ushort*)(ws + 105 * MBy); // 32 MB bf16 scores (dead after softmax)
    ushort* attn = (ushort*)(ws + 169 * MBy); // 32 MB (dead after ctx)
    // reuse (non-overlapping lifetimes):
    float*  ctx0 = (float*)(ws + 105 * MBy); // 32 MB over scb (dead after add2_cast)
    float*  ctx1 = (float*)(ws + 137 * MBy); // 32 MB (dead after add2_cast)
    ushort* ctxb = (ushort*)(ws + 25 * MBy); // 16 MB over xb (dead after wo)
    float*  ao0 = (float*)(ws + 105 * MBy);  // 32 MB over ctx0 (dead after ln1)
    float*  ao1 = (float*)(ws + 137 * MBy);  // 32 MB (dead after ln1)
    float*  x1  = (float*)(ws + 41 * MBy);   // 32 MB over qkv (live to ln2)
    ushort* x1b = (ushort*)(ws + 73 * MBy);  // 16 MB over qkv (dead after ffn1)
    ushort* h   = (ushort*)(ws + 105 * MBy); // 64 MB over ao (after ln1)
    float*  ff0 = (float*)(ws + 169 * MBy);  // 32 MB over attn
    float*  ff1 = (float*)(ws + 73 * MBy);   // 32 MB over x1b+vT (both dead by ffn2)

    dim3 b32(32, 8);

    // 1) cast x -> bf16
    cast_f2b4<<<(T * D) / 1024, 256, 0, stream>>>(x, xb, (long long)(T * D) / 4);

    // 2) transpose-cast weights: wq/wk/wv/wo -> [qkvT|woT] in ONE dispatch; w1, w2
    transpose4_to_bf16<<<dim3(32, 32, 4), b32, 0, stream>>>(wq, wk, wv, wo, qkvT);
    transpose_to_bf16<float><<<dim3(128, 32, 1), b32, 0, stream>>>(w1, w1T, D, F, F, 0, 0);
    transpose_to_bf16<float><<<dim3(32, 128, 1), b32, 0, stream>>>(w2, w2T, F, D, D, 0, 0);

    // 3) fused bias vector [bq|bk|bv]
    concat3<<<12, 256, 0, stream>>>(bq, bk, bv, bqkv);

    // 4) fused QKV projection: [T][1024] x [3072][1024]^T -> [T][3072] bf16 (384 blocks)
    gemm256<1, 0, 1><<<dim3(3 * D / 256, T / 256, 1), 512, 0, stream>>>(
        xb, qkvT, qkv, bqkv, D, 1, 1.f, D, D, 3 * D, 0, 0, 0, 0);

    // 5) V^T per batch: qkv v-slice [S][1024] (ld 3072) -> [D][S]
    transpose_to_bf16<ushort><<<dim3(D / 32, S / 32, Bz), b32, 0, stream>>>(
        qkv + 2048, vT, S, D, 3 * D, (long long)S * 3 * D, (long long)S * D);

    // 6) scores = Q K^T / 32 -> bf16; A=q, B=k slices of qkv (ld 3072) (256 blocks)
    gemm256<1, 0, 0><<<dim3(S / 256, S / 256, Bz), 512, 0, stream>>>(
        qkv, qkv + 1024, scb, nullptr, D, 1, 0.03125f, 3 * D, 3 * D, S,
        (long long)S * 3 * D, (long long)S * 3 * D, (long long)S * S, 0);

    // 7) softmax rows -> bf16 attn
    softmax_rows<<<T, 256, 0, stream>>>(scb, attn);

    // 8) ctx partials = attn @ V (BT = V^T [D][S]), split-K=2 -> fp32 (256 blocks)
    gemm256<0, 0, 0><<<dim3(D / 256, S / 256, Bz * 2), 512, 0, stream>>>(
        attn, vT, ctx0, nullptr, S, 2, 1.f, S, S, D,
        (long long)S * S, (long long)D * S, (long long)S * D, (long long)(ctx1 - ctx0));

    // 8b) ctx = ctx0 + ctx1 -> bf16
    add2_cast<<<(T * D) / 1024, 256, 0, stream>>>(ctx0, ctx1, ctxb, (long long)(T * D) / 4);

    // 9) attn_out partials = ctx @ wo^T (+bo chunk 0), split-K=2 (256 blocks)
    gemm256<0, 0, 1><<<dim3(D / 256, T / 256, 2), 512, 0, stream>>>(
        ctxb, woT, ao0, bo, D, 2, 1.f, D, D, D, 0, 0, 0, (long long)(ao1 - ao0));

    // 10) x1 = LN(x + ao0 + ao1) -> fp32 + bf16 (split-K reduction fused)
    residual_ln<<<T, 256, 0, stream>>>(x, ao0, ao1, g1, be1, x1, x1b);

    // 11) h = relu(x1 @ w1 + b1) (bf16, 512 blocks)
    gemm256<1, 1, 1><<<dim3(F / 256, T / 256, 1), 512, 0, stream>>>(
        x1b, w1T, h, b1, D, 1, 1.f, D, D, F, 0, 0, 0, 0);

    // 12) ff partials = h @ w2 (+b2 on chunk 0), split-K=2 (256 blocks)
    gemm256<0, 0, 1><<<dim3(D / 256, T / 256, 2), 512, 0, stream>>>(
        h, w2T, ff0, b2, F, 2, 1.f, F, F, D, 0, 0, 0, (long long)(ff1 - ff0));

    // 13) out = LN(x1 + ff0 + ff1) -> d_out fp32 (split-K reduction fused)
    residual_ln<<<T, 256, 0, stream>>>(x1, ff0, ff1, g2, be2, out, nullptr);
}

// Round 4
// 567.688 us; speedup vs baseline: 1.0142x; 1.0142x over previous
//
#include <hip/hip_runtime.h>
#include <stdint.h>

// ---------------- common helpers ----------------

using f32x4 = __attribute__((ext_vector_type(4))) float;
using s16x8 = __attribute__((ext_vector_type(8))) short;

__device__ __forceinline__ ushort f2b(float f) {
    union { float f; uint32_t u; } v; v.f = f;
    uint32_t u = v.u;
    return (ushort)((u + 0x7fffu + ((u >> 16) & 1u)) >> 16);
}
__device__ __forceinline__ float b2f(ushort b) {
    union { uint32_t u; float f; } v; v.u = ((uint32_t)b) << 16;
    return v.f;
}
__device__ __forceinline__ float to_f(float f) { return f; }
__device__ __forceinline__ float to_f(ushort b) { return b2f(b); }

// async global->LDS, 16B per lane; LDS dest = wave-uniform base + lane*16
__device__ __forceinline__ void async_ld16(const ushort* g, ushort* l) {
    __builtin_amdgcn_global_load_lds(
        (const __attribute__((address_space(1))) void*)g,
        (__attribute__((address_space(3))) void*)l,
        16, 0, 0);
}

// s_waitcnt immediates (gfx9): vmcnt[3:0]|[15:14], expcnt[6:4], lgkmcnt[11:8]
#define WAITCNT_VM4    0x0F74  // vmcnt=4, lgkm/exp no-wait
#define WAITCNT_VM0    0x0F70  // vmcnt=0
#define WAITCNT_LGKM12 0xCC7F  // lgkmcnt=12, vmcnt/exp no-wait
#define WAITCNT_LGKM0  0xC07F  // lgkmcnt=0

// ---------------- cast fp32 -> bf16 (vectorized x4) ----------------

__global__ __launch_bounds__(256) void cast_f2b4(const float* __restrict__ src,
                                                 ushort* __restrict__ dst,
                                                 long long n4) {
    long long i = (long long)blockIdx.x * 256 + threadIdx.x;
    if (i >= n4) return;
    float4 f = ((const float4*)src)[i];
    ushort4 o;
    o.x = f2b(f.x); o.y = f2b(f.y); o.z = f2b(f.z); o.w = f2b(f.w);
    ((ushort4*)dst)[i] = o;
}

// ---------------- bias concat: [bq|bk|bv] -> dst (3*1024 floats) ----------------

__global__ __launch_bounds__(256) void concat3(const float* __restrict__ a,
                                               const float* __restrict__ b,
                                               const float* __restrict__ c,
                                               float* __restrict__ dst) {
    int i = blockIdx.x * 256 + threadIdx.x;  // grid 12 blocks = 3072
    const float* s = (i < 1024) ? a : (i < 2048) ? b : c;
    dst[i] = s[i & 1023];
}

// ---------------- split-K partial reduce + cast to bf16 --------------------------

__global__ __launch_bounds__(256) void add2_cast(const float* __restrict__ a,
                                                 const float* __restrict__ b,
                                                 ushort* __restrict__ o,
                                                 long long n4) {
    long long i = (long long)blockIdx.x * 256 + threadIdx.x;
    if (i >= n4) return;
    float4 x = ((const float4*)a)[i];
    float4 y = ((const float4*)b)[i];
    ushort4 u;
    u.x = f2b(x.x + y.x); u.y = f2b(x.y + y.y);
    u.z = f2b(x.z + y.z); u.w = f2b(x.w + y.w);
    ((ushort4*)o)[i] = u;
}

// ---------------- transpose (fp32 or bf16 in) -> bf16 out ----------------
// src: [R][C] with row stride srcLd, dst: [C][R] row-major.
// Grid: (C/32, R/32, batch), block (32,8).

template <typename T>
__global__ __launch_bounds__(256) void transpose_to_bf16(const T* __restrict__ src,
                                                         ushort* __restrict__ dst,
                                                         int R, int C, int srcLd,
                                                         long long ss, long long ds) {
    __shared__ float tile[32][33];
    src += (long long)blockIdx.z * ss;
    dst += (long long)blockIdx.z * ds;
    const int c0 = blockIdx.x * 32;
    const int r0 = blockIdx.y * 32;
    const int tx = threadIdx.x, ty = threadIdx.y;
#pragma unroll
    for (int i = 0; i < 4; i++) {
        int r = r0 + ty + i * 8;
        tile[ty + i * 8][tx] = to_f(src[(long long)r * srcLd + c0 + tx]);
    }
    __syncthreads();
#pragma unroll
    for (int i = 0; i < 4; i++) {
        int r = c0 + ty + i * 8;  // row of dst, in [0, C)
        dst[(long long)r * R + r0 + tx] = f2b(tile[tx][ty + i * 8]);
    }
}

// ---- fused 4x (1024x1024) transpose-cast: z selects {wq,wk,wv,wo}, dst contiguous ----

__global__ __launch_bounds__(256) void transpose4_to_bf16(const float* __restrict__ s0,
                                                          const float* __restrict__ s1,
                                                          const float* __restrict__ s2,
                                                          const float* __restrict__ s3,
                                                          ushort* __restrict__ dst) {
    __shared__ float tile[32][33];
    const int D = 1024;
    const int z = blockIdx.z;
    const float* src = (z == 0) ? s0 : (z == 1) ? s1 : (z == 2) ? s2 : s3;
    dst += (long long)z * D * D;
    const int c0 = blockIdx.x * 32;
    const int r0 = blockIdx.y * 32;
    const int tx = threadIdx.x, ty = threadIdx.y;
#pragma unroll
    for (int i = 0; i < 4; i++) {
        int r = r0 + ty + i * 8;
        tile[ty + i * 8][tx] = src[(long long)r * D + c0 + tx];
    }
    __syncthreads();
#pragma unroll
    for (int i = 0; i < 4; i++) {
        int r = c0 + ty + i * 8;
        dst[(long long)r * D + r0 + tx] = f2b(tile[tx][ty + i * 8]);
    }
}

// ---------------- bf16 MFMA GEMM, 256x256 tile, 4-buffer BK=32 pipeline ----------
// C[M,N] = A[M,K] * BT[N,K]^T (+bias, relu, scale). 512 threads = 8 waves (2M x 4N),
// per-wave 128x64 output = acc[8][4] f32x4. Structure per R3 (one barrier/K-tile,
// frags register-prefetched one tile ahead, counted lgkm/vm waits, 4x32KB bufs).
//
// R4 fix: LDS slot swizzle. R3 measured 6.29M SQ_LDS_BANK_CONFLICT: at 64B rows,
// bank = 16*(row&1) + 4*slot (only row bit 0 reaches bank index), so a b128
// frag-read pass (8 lanes, fixed slot=quad, rows 0..7) hits one bank quartet
// 4 ways. Fix: physical 16B slot = logical slot ^ ((row>>1)&3) -- an 8-lane pass
// then covers all 8 bank quartets exactly once (conflict-free). The XOR depends
// only on row bits 1-2, identical across staging-local row (lr), A-frag row
// (wm*128+l16), B-frag row (wn*64+l16) -> one involution both sides (rule #21):
// inverse-swizzled GLOBAL source (LDS dest of global_load_lds stays linear) +
// swizzled frag-read slot. Global src stays in the same 64B span per 4-lane
// group -> coalescing unaffected.
// Epilogue: R2's LDS-staged coalesced C-write (verified: WRITE_SIZE == logical).
// Split-K (kChunks>1): chunk kIdx writes partials at C + kIdx*sK; bias chunk 0 only.

template <int OUT_BF16, int RELU, int HAS_BIAS>
__global__ __launch_bounds__(512, 2) void gemm256(const ushort* __restrict__ A,
                                                  const ushort* __restrict__ BT,
                                                  void* __restrict__ Cp,
                                                  const float* __restrict__ bias,
                                                  int K, int kChunks, float scale,
                                                  int lda, int ldb, int ldc,
                                                  long long sA, long long sB,
                                                  long long sC, long long sK) {
    __shared__ ushort SH[65536];   // 128 KB: A bufs [4][256][32] @0, B bufs @+32768 elems
    ushort* Asl = SH;
    ushort* Bsl = SH + 32768;

    const int tid = threadIdx.x;
    const int kIdx = blockIdx.z % kChunks;
    const int bz = blockIdx.z / kChunks;
    const int kLen = K / kChunks;
    const int kOff = kIdx * kLen;
    const int kTiles = kLen >> 5;   // BK=32
    const ushort* Ab = A + (long long)bz * sA;
    const ushort* Bb = BT + (long long)bz * sB;

    // XCD-panel swizzle (T1; bijective since gridDim.y % 8 == 0 for all our grids)
    const int W = gridDim.x, H = gridDim.y;
    const int bidx = blockIdx.y * W + blockIdx.x;
    const int Hp = H >> 3;
    const int xcd = bidx & 7;
    const int sb = bidx >> 3;
    const int tn = sb / Hp;
    const int tm = xcd * Hp + sb % Hp;

    const int lane = tid & 63;
    const int w = tid >> 6;    // wave 0..7
    const int wm = w >> 2;     // M half 0..1
    const int wn = w & 3;      // N quarter 0..3
    const int l16 = lane & 15;
    const int quad = lane >> 4;

    // ---- staging: per tile A = 16 KB = 16 x 1KB instr (2/wave), B same.
    // instr covers 16 rows x 32 cols; lane l -> LDS row (l>>2), phys slot (l&3).
    // Source fetches logical slot (l&3) ^ ((lr>>1)&3)  [bank swizzle, see header].
    const int lr = lane >> 2;                                // 0..15
    const int lc = ((lane & 3) ^ ((lane >> 3) & 3)) * 8;     // swizzled source chunk
    const ushort* AgS = Ab + (long long)(tm * 256 + w * 32 + lr) * lda + kOff + lc;
    const ushort* BgS = Bb + (long long)(tn * 256 + w * 32 + lr) * ldb + kOff + lc;
    ushort* AsW = Asl + w * 1024;    // wave's 32 rows within a buf
    ushort* BsW = Bsl + w * 1024;
    const long long rstepA = (long long)16 * lda;
    const long long rstepB = (long long)16 * ldb;

#define STG(tt) { const int bf_ = (tt) & 3;                                       \
        const ushort* ga_ = AgS + (tt) * 32; const ushort* gb_ = BgS + (tt) * 32; \
        async_ld16(ga_, AsW + bf_ * 8192);                                        \
        async_ld16(ga_ + rstepA, AsW + bf_ * 8192 + 512);                         \
        async_ld16(gb_, BsW + bf_ * 8192);                                        \
        async_ld16(gb_ + rstepB, BsW + bf_ * 8192 + 512); }

    // ---- fragment read bases (elem offsets into row-major [256][32] buf)
    // physical slot = quad ^ ((row>>1)&3); row bits 1-2 == l16 bits 1-2.
    const int fsl = (quad ^ ((l16 >> 1) & 3)) * 8;
    const ushort* ArdB = Asl + (wm * 128 + l16) * 32 + fsl;  // + i*512 + bf*8192
    const ushort* BrdB = Bsl + (wn * 64 + l16) * 32 + fsl;   // + j*512 + bf*8192

#define LDF(pre, tt) { const int bf_ = (tt) & 3;                                  \
        const ushort* Ar_ = ArdB + bf_ * 8192;                                    \
        const ushort* Br_ = BrdB + bf_ * 8192;                                    \
        _Pragma("unroll") for (int i_ = 0; i_ < 8; i_++)                          \
            pre##a[i_] = *(const s16x8*)(Ar_ + i_ * 512);                         \
        _Pragma("unroll") for (int j_ = 0; j_ < 4; j_++)                          \
            pre##b[j_] = *(const s16x8*)(Br_ + j_ * 512); }

#define MM(pre) {                                                                 \
        __builtin_amdgcn_sched_barrier(0);                                        \
        __builtin_amdgcn_s_setprio(1);                                            \
        _Pragma("unroll") for (int i_ = 0; i_ < 8; i_++)                          \
            _Pragma("unroll") for (int j_ = 0; j_ < 4; j_++)                      \
                acc[i_][j_] = __builtin_amdgcn_mfma_f32_16x16x32_bf16(            \
                    pre##a[i_], pre##b[j_], acc[i_][j_], 0, 0, 0);                \
        __builtin_amdgcn_s_setprio(0);                                            \
        __builtin_amdgcn_sched_barrier(0); }

    f32x4 acc[8][4];
#pragma unroll
    for (int i = 0; i < 8; i++)
#pragma unroll
        for (int j = 0; j < 4; j++) acc[i][j] = (f32x4){0.f, 0.f, 0.f, 0.f};

    s16x8 fca[8], fna[8];
    s16x8 fcb[4], fnb[4];

    // ---- prologue: stage tiles 0,1,2; publish 0,1; prefetch frags(0)
    STG(0); STG(1); STG(2);
    __builtin_amdgcn_s_waitcnt(WAITCNT_VM4);   // tiles 0,1 landed; tile 2 in flight
    __builtin_amdgcn_s_barrier();              // publish 0,1
    LDF(fc, 0);

    for (int t = 0; t < kTiles; t += 2) {
        // ---- even iter: consume fc(t), prefetch fn(t+1)
        if (t + 1 < kTiles) LDF(fn, t + 1);
        if (t + 3 < kTiles) STG(t + 3);
        if (t + 1 < kTiles) __builtin_amdgcn_s_waitcnt(WAITCNT_LGKM12);
        else                __builtin_amdgcn_s_waitcnt(WAITCNT_LGKM0);
        MM(fc);
        if (t + 2 < kTiles) {
            if (t + 3 < kTiles) __builtin_amdgcn_s_waitcnt(WAITCNT_VM4);
            else                __builtin_amdgcn_s_waitcnt(WAITCNT_VM0);
            __builtin_amdgcn_s_barrier();      // publish t+2
        }
        // ---- odd iter: consume fn(t+1), prefetch fc(t+2)
        if (t + 1 < kTiles) {
            if (t + 2 < kTiles) LDF(fc, t + 2);
            if (t + 4 < kTiles) STG(t + 4);
            if (t + 2 < kTiles) __builtin_amdgcn_s_waitcnt(WAITCNT_LGKM12);
            else                __builtin_amdgcn_s_waitcnt(WAITCNT_LGKM0);
            MM(fn);
            if (t + 3 < kTiles) {
                if (t + 4 < kTiles) __builtin_amdgcn_s_waitcnt(WAITCNT_VM4);
                else                __builtin_amdgcn_s_waitcnt(WAITCNT_VM0);
                __builtin_amdgcn_s_barrier();  // publish t+3
            }
        }
    }
#undef STG
#undef LDF
#undef MM

    __builtin_amdgcn_s_barrier();  // all waves' frag reads retired before C-staging

    // ---- epilogue: acc C/D layout col = lane&15, row = quad*4 + reg [m89/m91].
    // Stage into LDS (group-XOR ^quad -> conflict-free writes; full-row reads),
    // then fully-coalesced global stores (R2-verified: WRITE_SIZE == logical).
    const long long cb = (long long)bz * sC + (long long)kIdx * sK;
    if (OUT_BF16) {
        ushort* Cb = (ushort*)Cp;
        // stage: SH as [256 rows][16 groups of 16 ushorts], group ^= quad
#pragma unroll
        for (int j = 0; j < 4; j++) {
            const int cg = wn * 4 + j;  // col group (col>>4), uniform per wave
            const float bv = HAS_BIAS ? bias[tn * 256 + cg * 16 + l16] : 0.0f;
#pragma unroll
            for (int i = 0; i < 8; i++) {
                const int rbase = wm * 128 + i * 16 + quad * 4;
#pragma unroll
                for (int r = 0; r < 4; r++) {
                    const int row = rbase + r;
                    float v = acc[i][j][r] * scale + bv;
                    if (RELU) v = v > 0.f ? v : 0.f;
                    SH[row * 256 + ((cg ^ ((row >> 2) & 3)) << 4) + l16] = f2b(v);
                }
            }
        }
        __builtin_amdgcn_s_barrier();
        // readout: 16 passes x (16 rows x 32 chunks of 16B); 512B contiguous/row
        const int crow = tid >> 5;  // 0..15
        const int cch = tid & 31;   // 0..31
        const int g = cch >> 1, hh = cch & 1;
#pragma unroll
        for (int pass = 0; pass < 16; pass++) {
            const int row = pass * 16 + crow;
            s16x8 vv = *(const s16x8*)&SH[row * 256 + ((g ^ ((row >> 2) & 3)) << 4) + hh * 8];
            *(s16x8*)&Cb[cb + (long long)(tm * 256 + row) * ldc + tn * 256 + cch * 8] = vv;
        }
    } else {
        float* Cf = (float*)Cp;
        float* SHf = (float*)SH;  // [128 rows][32 groups of 8 floats] per half-pass
#pragma unroll
        for (int half = 0; half < 2; half++) {
            if (wm == half) {
#pragma unroll
                for (int j = 0; j < 4; j++) {
                    const int col = wn * 64 + j * 16 + l16;
                    const float bv = (HAS_BIAS && kIdx == 0) ? bias[tn * 256 + col] : 0.0f;
                    const int gg = col >> 3, cl = col & 7;
#pragma unroll
                    for (int i = 0; i < 8; i++) {
                        const int rbase = i * 16 + quad * 4;  // row within half
#pragma unroll
                        for (int r = 0; r < 4; r++) {
                            const int row = rbase + r;
                            float v = acc[i][j][r] * scale + bv;
                            if (RELU) v = v > 0.f ? v : 0.f;
                            SHf[row * 256 + ((gg ^ ((row >> 2) & 3)) << 3) + cl] = v;
                        }
                    }
                }
            }
            __builtin_amdgcn_s_barrier();
            // readout: 16 passes x (8 rows x 64 chunks of 16B); 1024B contiguous/row
            const int rr = tid >> 6, cc = tid & 63;
            const int g2 = cc >> 1, h2 = cc & 1;
#pragma unroll
            for (int pass = 0; pass < 16; pass++) {
                const int row = pass * 8 + rr;
                f32x4 vv = *(const f32x4*)&SHf[row * 256 + ((g2 ^ ((row >> 2) & 3)) << 3) + h2 * 4];
                *(f32x4*)&Cf[cb + (long long)(tm * 256 + half * 128 + row) * ldc + tn * 256 + cc * 4] = vv;
            }
            __builtin_amdgcn_s_barrier();
        }
    }
}

// ---------------- row softmax: bf16 [rows][2048] -> bf16, vectorized 8/thread -------

__global__ __launch_bounds__(256) void softmax_rows(const ushort* __restrict__ S,
                                                    ushort* __restrict__ P) {
    const int C = 2048;
    const long long row = blockIdx.x;
    const int tid = threadIdx.x;
    const ushort4* s4 = (const ushort4*)(S + row * C) + tid * 2;  // 8 contiguous elems
    ushort4 a = s4[0], bq = s4[1];
    float v[8];
    v[0] = b2f(a.x); v[1] = b2f(a.y); v[2] = b2f(a.z); v[3] = b2f(a.w);
    v[4] = b2f(bq.x); v[5] = b2f(bq.y); v[6] = b2f(bq.z); v[7] = b2f(bq.w);
    float mx = -1e30f;
#pragma unroll
    for (int i = 0; i < 8; i++) mx = fmaxf(mx, v[i]);
    __shared__ float red[256];
    red[tid] = mx;
    __syncthreads();
    for (int off = 128; off > 0; off >>= 1) {
        if (tid < off) red[tid] = fmaxf(red[tid], red[tid + off]);
        __syncthreads();
    }
    mx = red[0];
    __syncthreads();
    float sum = 0.f;
#pragma unroll
    for (int i = 0; i < 8; i++) {
        v[i] = __expf(v[i] - mx);
        sum += v[i];
    }
    red[tid] = sum;
    __syncthreads();
    for (int off = 128; off > 0; off >>= 1) {
        if (tid < off) red[tid] += red[tid + off];
        __syncthreads();
    }
    float inv = 1.f / red[0];
    ushort4 o0, o1;
    o0.x = f2b(v[0] * inv); o0.y = f2b(v[1] * inv); o0.z = f2b(v[2] * inv); o0.w = f2b(v[3] * inv);
    o1.x = f2b(v[4] * inv); o1.y = f2b(v[5] * inv); o1.z = f2b(v[6] * inv); o1.w = f2b(v[7] * inv);
    ushort4* p4 = (ushort4*)(P + row * C) + tid * 2;
    p4[0] = o0;
    p4[1] = o1;
}

// ---------------- fused residual(+partial-sum) + LayerNorm (D=1024) ----------------
// out = LN(X + Y + (Y2?)) ; Y2 nullable (split-K partial reduction fused here).

__global__ __launch_bounds__(256) void residual_ln(const float* __restrict__ X,
                                                   const float* __restrict__ Y,
                                                   const float* __restrict__ Y2,
                                                   const float* __restrict__ g,
                                                   const float* __restrict__ be,
                                                   float* __restrict__ outf,
                                                   ushort* __restrict__ outb) {
    const int D = 1024;
    const long long row = blockIdx.x;
    const float* x = X + row * D;
    const float* y = Y + row * D;
    const float* y2 = Y2 ? Y2 + row * D : nullptr;
    const int tid = threadIdx.x;
    float v[4];
    float s = 0.f, s2 = 0.f;
#pragma unroll
    for (int i = 0; i < 4; i++) {
        int c = tid + i * 256;
        float t = x[c] + y[c];
        if (y2) t += y2[c];
        v[i] = t;
        s += t;
        s2 += t * t;
    }
    __shared__ float r1[256], r2[256];
    r1[tid] = s;
    r2[tid] = s2;
    __syncthreads();
    for (int off = 128; off > 0; off >>= 1) {
        if (tid < off) {
            r1[tid] += r1[tid + off];
            r2[tid] += r2[tid + off];
        }
        __syncthreads();
    }
    float mu = r1[0] * (1.f / 1024.f);
    float var = r2[0] * (1.f / 1024.f) - mu * mu;
    float inv = rsqrtf(var + 1e-5f);
    float* of = outf + row * D;
    ushort* ob = outb ? outb + row * D : nullptr;
#pragma unroll
    for (int i = 0; i < 4; i++) {
        int c = tid + i * 256;
        float o = (v[i] - mu) * inv * g[c] + be[c];
        of[c] = o;
        if (ob) ob[c] = f2b(o);
    }
}

// ---------------- launch ----------------

extern "C" void kernel_launch(void* const* d_in, const int* in_sizes, int n_in,
                              void* d_out, int out_size, void* d_ws, size_t ws_size,
                              hipStream_t stream) {
    const float* x  = (const float*)d_in[0];
    const float* wq = (const float*)d_in[1];
    const float* bq = (const float*)d_in[2];
    const float* wk = (const float*)d_in[3];
    const float* bk = (const float*)d_in[4];
    const float* wv = (const float*)d_in[5];
    const float* bv = (const float*)d_in[6];
    const float* wo = (const float*)d_in[7];
    const float* bo = (const float*)d_in[8];
    const float* w1 = (const float*)d_in[9];
    const float* b1 = (const float*)d_in[10];
    const float* w2 = (const float*)d_in[11];
    const float* b2 = (const float*)d_in[12];
    const float* g1 = (const float*)d_in[13];
    const float* be1 = (const float*)d_in[14];
    const float* g2 = (const float*)d_in[15];
    const float* be2 = (const float*)d_in[16];
    float* out = (float*)d_out;
    char* ws = (char*)d_ws;

    const int Bz = 4, S = 2048, D = 1024, F = 4096;
    const int T = Bz * S;  // 8192 rows
    const size_t MBy = 1024ull * 1024ull;

    // workspace layout (byte offsets), lifetime-based reuse; peak 201 MB
    ushort* qkvT = (ushort*)(ws + 0);        // 6 MB  [3072][1024]; woT follows contiguously
    ushort* woT  = (ushort*)(ws + 6 * MBy);  // 2 MB
    ushort* w1T  = (ushort*)(ws + 8 * MBy);  // 8 MB   [F][D]
    ushort* w2T  = (ushort*)(ws + 16 * MBy); // 8 MB   [D][F]
    float*  bqkv = (float*)(ws + 24 * MBy);  // 12 KB  (dead after QKV gemm)
    ushort* xb   = (ushort*)(ws + 25 * MBy); // 16 MB  (dead after QKV gemm)
    ushort* qkv  = (ushort*)(ws + 41 * MBy); // 48 MB  [T][3072] (dead after scores+vT)
    ushort* vT   = (ushort*)(ws + 89 * MBy); // 16 MB  [B][D][S] (dead after ctx)
    ushort* scb  = (ushort*)(ws + 105 * MBy); // 32 MB bf16 scores (dead after softmax)
    ushort* attn = (ushort*)(ws + 169 * MBy); // 32 MB (dead after ctx)
    // reuse (non-overlapping lifetimes):
    float*  ctx0 = (float*)(ws + 105 * MBy); // 32 MB over scb (dead after add2_cast)
    float*  ctx1 = (float*)(ws + 137 * MBy); // 32 MB (dead after add2_cast)
    ushort* ctxb = (ushort*)(ws + 25 * MBy); // 16 MB over xb (dead after wo)
    float*  ao0 = (float*)(ws + 105 * MBy);  // 32 MB over ctx0 (dead after ln1)
    float*  ao1 = (float*)(ws + 137 * MBy);  // 32 MB (dead after ln1)
    float*  x1  = (float*)(ws + 41 * MBy);   // 32 MB over qkv (live to ln2)
    ushort* x1b = (ushort*)(ws + 73 * MBy);  // 16 MB over qkv (dead after ffn1)
    ushort* h   = (ushort*)(ws + 105 * MBy); // 64 MB over ao (after ln1)
    float*  ff0 = (float*)(ws + 169 * MBy);  // 32 MB over attn
    float*  ff1 = (float*)(ws + 73 * MBy);   // 32 MB over x1b+vT (both dead by ffn2)

    dim3 b32(32, 8);

    // 1) cast x -> bf16
    cast_f2b4<<<(T * D) / 1024, 256, 0, stream>>>(x, xb, (long long)(T * D) / 4);

    // 2) transpose-cast weights: wq/wk/wv/wo -> [qkvT|woT] in ONE dispatch; w1, w2
    transpose4_to_bf16<<<dim3(32, 32, 4), b32, 0, stream>>>(wq, wk, wv, wo, qkvT);
    transpose_to_bf16<float><<<dim3(128, 32, 1), b32, 0, stream>>>(w1, w1T, D, F, F, 0, 0);
    transpose_to_bf16<float><<<dim3(32, 128, 1), b32, 0, stream>>>(w2, w2T, F, D, D, 0, 0);

    // 3) fused bias vector [bq|bk|bv]
    concat3<<<12, 256, 0, stream>>>(bq, bk, bv, bqkv);

    // 4) fused QKV projection: [T][1024] x [3072][1024]^T -> [T][3072] bf16 (384 blocks)
    gemm256<1, 0, 1><<<dim3(3 * D / 256, T / 256, 1), 512, 0, stream>>>(
        xb, qkvT, qkv, bqkv, D, 1, 1.f, D, D, 3 * D, 0, 0, 0, 0);

    // 5) V^T per batch: qkv v-slice [S][1024] (ld 3072) -> [D][S]
    transpose_to_bf16<ushort><<<dim3(D / 32, S / 32, Bz), b32, 0, stream>>>(
        qkv + 2048, vT, S, D, 3 * D, (long long)S * 3 * D, (long long)S * D);

    // 6) scores = Q K^T / 32 -> bf16; A=q, B=k slices of qkv (ld 3072) (256 blocks)
    gemm256<1, 0, 0><<<dim3(S / 256, S / 256, Bz), 512, 0, stream>>>(
        qkv, qkv + 1024, scb, nullptr, D, 1, 0.03125f, 3 * D, 3 * D, S,
        (long long)S * 3 * D, (long long)S * 3 * D, (long long)S * S, 0);

    // 7) softmax rows -> bf16 attn
    softmax_rows<<<T, 256, 0, stream>>>(scb, attn);

    // 8) ctx partials = attn @ V (BT = V^T [D][S]), split-K=2 -> fp32 (256 blocks)
    gemm256<0, 0, 0><<<dim3(D / 256, S / 256, Bz * 2), 512, 0, stream>>>(
        attn, vT, ctx0, nullptr, S, 2, 1.f, S, S, D,
        (long long)S * S, (long long)D * S, (long long)S * D, (long long)(ctx1 - ctx0));

    // 8b) ctx = ctx0 + ctx1 -> bf16
    add2_cast<<<(T * D) / 1024, 256, 0, stream>>>(ctx0, ctx1, ctxb, (long long)(T * D) / 4);

    // 9) attn_out partials = ctx @ wo^T (+bo chunk 0), split-K=2 (256 blocks)
    gemm256<0, 0, 1><<<dim3(D / 256, T / 256, 2), 512, 0, stream>>>(
        ctxb, woT, ao0, bo, D, 2, 1.f, D, D, D, 0, 0, 0, (long long)(ao1 - ao0));

    // 10) x1 = LN(x + ao0 + ao1) -> fp32 + bf16 (split-K reduction fused)
    residual_ln<<<T, 256, 0, stream>>>(x, ao0, ao1, g1, be1, x1, x1b);

    // 11) h = relu(x1 @ w1 + b1) (bf16, 512 blocks)
    gemm256<1, 1, 1><<<dim3(F / 256, T / 256, 1), 512, 0, stream>>>(
        x1b, w1T, h, b1, D, 1, 1.f, D, D, F, 0, 0, 0, 0);

    // 12) ff partials = h @ w2 (+b2 on chunk 0), split-K=2 (256 blocks)
    gemm256<0, 0, 1><<<dim3(D / 256, T / 256, 2), 512, 0, stream>>>(
        h, w2T, ff0, b2, F, 2, 1.f, F, F, D, 0, 0, 0, (long long)(ff1 - ff0));

    // 13) out = LN(x1 + ff0 + ff1) -> d_out fp32 (split-K reduction fused)
    residual_ln<<<T, 256, 0, stream>>>(x1, ff0, ff1, g2, be2, out, nullptr);
}

// Round 5
// 562.399 us; speedup vs baseline: 1.0238x; 1.0094x over previous
//
#include <hip/hip_runtime.h>
#include <stdint.h>

// ---------------- common helpers ----------------

using f32x4 = __attribute__((ext_vector_type(4))) float;
using s16x8 = __attribute__((ext_vector_type(8))) short;

__device__ __forceinline__ ushort f2b(float f) {
    union { float f; uint32_t u; } v; v.f = f;
    uint32_t u = v.u;
    return (ushort)((u + 0x7fffu + ((u >> 16) & 1u)) >> 16);
}
__device__ __forceinline__ float b2f(ushort b) {
    union { uint32_t u; float f; } v; v.u = ((uint32_t)b) << 16;
    return v.f;
}
__device__ __forceinline__ float to_f(float f) { return f; }
__device__ __forceinline__ float to_f(ushort b) { return b2f(b); }

// async global->LDS, 16B per lane; LDS dest = wave-uniform base + lane*16
__device__ __forceinline__ void async_ld16(const ushort* g, ushort* l) {
    __builtin_amdgcn_global_load_lds(
        (const __attribute__((address_space(1))) void*)g,
        (__attribute__((address_space(3))) void*)l,
        16, 0, 0);
}

// s_waitcnt immediates (gfx9): vmcnt[3:0]|[15:14], expcnt[6:4], lgkmcnt[11:8]
#define WAITCNT_VM4    0x0F74  // vmcnt=4, lgkm/exp no-wait
#define WAITCNT_VM0    0x0F70  // vmcnt=0
#define WAITCNT_LGKM12 0xCC7F  // lgkmcnt=12, vmcnt/exp no-wait
#define WAITCNT_LGKM0  0xC07F  // lgkmcnt=0

// ---------------- cast fp32 -> bf16 (vectorized x4) ----------------

__global__ __launch_bounds__(256) void cast_f2b4(const float* __restrict__ src,
                                                 ushort* __restrict__ dst,
                                                 long long n4) {
    long long i = (long long)blockIdx.x * 256 + threadIdx.x;
    if (i >= n4) return;
    float4 f = ((const float4*)src)[i];
    ushort4 o;
    o.x = f2b(f.x); o.y = f2b(f.y); o.z = f2b(f.z); o.w = f2b(f.w);
    ((ushort4*)dst)[i] = o;
}

// ---------------- bias concat: [bq|bk|bv] -> dst (3*1024 floats) ----------------

__global__ __launch_bounds__(256) void concat3(const float* __restrict__ a,
                                               const float* __restrict__ b,
                                               const float* __restrict__ c,
                                               float* __restrict__ dst) {
    int i = blockIdx.x * 256 + threadIdx.x;  // grid 12 blocks = 3072
    const float* s = (i < 1024) ? a : (i < 2048) ? b : c;
    dst[i] = s[i & 1023];
}

// ---------------- split-K partial reduce + cast to bf16 --------------------------

__global__ __launch_bounds__(256) void add2_cast(const float* __restrict__ a,
                                                 const float* __restrict__ b,
                                                 ushort* __restrict__ o,
                                                 long long n4) {
    long long i = (long long)blockIdx.x * 256 + threadIdx.x;
    if (i >= n4) return;
    float4 x = ((const float4*)a)[i];
    float4 y = ((const float4*)b)[i];
    ushort4 u;
    u.x = f2b(x.x + y.x); u.y = f2b(x.y + y.y);
    u.z = f2b(x.z + y.z); u.w = f2b(x.w + y.w);
    ((ushort4*)o)[i] = u;
}

// ---------------- transpose (fp32 or bf16 in) -> bf16 out ----------------
// src: [R][C] with row stride srcLd, dst: [C][R] row-major.
// Grid: (C/32, R/32, batch), block (32,8).

template <typename T>
__global__ __launch_bounds__(256) void transpose_to_bf16(const T* __restrict__ src,
                                                         ushort* __restrict__ dst,
                                                         int R, int C, int srcLd,
                                                         long long ss, long long ds) {
    __shared__ float tile[32][33];
    src += (long long)blockIdx.z * ss;
    dst += (long long)blockIdx.z * ds;
    const int c0 = blockIdx.x * 32;
    const int r0 = blockIdx.y * 32;
    const int tx = threadIdx.x, ty = threadIdx.y;
#pragma unroll
    for (int i = 0; i < 4; i++) {
        int r = r0 + ty + i * 8;
        tile[ty + i * 8][tx] = to_f(src[(long long)r * srcLd + c0 + tx]);
    }
    __syncthreads();
#pragma unroll
    for (int i = 0; i < 4; i++) {
        int r = c0 + ty + i * 8;  // row of dst, in [0, C)
        dst[(long long)r * R + r0 + tx] = f2b(tile[tx][ty + i * 8]);
    }
}

// ---- fused 4x (1024x1024) transpose-cast: z selects {wq,wk,wv,wo}, dst contiguous ----

__global__ __launch_bounds__(256) void transpose4_to_bf16(const float* __restrict__ s0,
                                                          const float* __restrict__ s1,
                                                          const float* __restrict__ s2,
                                                          const float* __restrict__ s3,
                                                          ushort* __restrict__ dst) {
    __shared__ float tile[32][33];
    const int D = 1024;
    const int z = blockIdx.z;
    const float* src = (z == 0) ? s0 : (z == 1) ? s1 : (z == 2) ? s2 : s3;
    dst += (long long)z * D * D;
    const int c0 = blockIdx.x * 32;
    const int r0 = blockIdx.y * 32;
    const int tx = threadIdx.x, ty = threadIdx.y;
#pragma unroll
    for (int i = 0; i < 4; i++) {
        int r = r0 + ty + i * 8;
        tile[ty + i * 8][tx] = src[(long long)r * D + c0 + tx];
    }
    __syncthreads();
#pragma unroll
    for (int i = 0; i < 4; i++) {
        int r = c0 + ty + i * 8;
        dst[(long long)r * D + r0 + tx] = f2b(tile[tx][ty + i * 8]);
    }
}

// ---------------- bf16 MFMA GEMM, 256x256 tile, 4-buffer BK=32 pipeline ----------
// C[M,N] = A[M,K] * BT[N,K]^T (+bias, relu, scale). 512 threads = 8 waves (2M x 4N),
// per-wave 128x64 output = acc[8][4] f32x4. One barrier per K-tile, frags
// register-prefetched one tile ahead, counted lgkm/vm waits, 4x32KB LDS bufs,
// bank swizzle phys_slot = log_slot ^ ((row>>1)&3) (R4-verified: conflicts = 0).
//
// R5 change (R4 post-mortem: 2993 cyc/tile vs 1242 MFMA floor, MfmaUtil 36% with
// conflicts=0 and waits ~0 -> the schedule was COMPILER-PINNED by sched_barrier(0)
// around the MFMA cluster, forbidding mem-issue/addr-calc/MFMA interleave =
// Common-mistake #5 / m141): (1) drop sched_barrier + setprio (m190: setprio null
// for lockstep GEMM), let the compiler co-schedule; data deps via IR loads keep
// correctness; barriers/waitcnt builtins stay as hard fences. (2) unroll steady
// state 4x so buffer indices are compile-time -> ds_read bases become offset:imm
// (no per-iter address VALU). Guarded tail (R4 loop) for the last tiles.
// Epilogue: R2's LDS-staged coalesced C-write (verified: WRITE_SIZE == logical).
// Split-K (kChunks>1): chunk kIdx writes partials at C + kIdx*sK; bias chunk 0 only.

template <int OUT_BF16, int RELU, int HAS_BIAS>
__global__ __launch_bounds__(512, 2) void gemm256(const ushort* __restrict__ A,
                                                  const ushort* __restrict__ BT,
                                                  void* __restrict__ Cp,
                                                  const float* __restrict__ bias,
                                                  int K, int kChunks, float scale,
                                                  int lda, int ldb, int ldc,
                                                  long long sA, long long sB,
                                                  long long sC, long long sK) {
    __shared__ ushort SH[65536];   // 128 KB: A bufs [4][256][32] @0, B bufs @+32768 elems
    ushort* Asl = SH;
    ushort* Bsl = SH + 32768;

    const int tid = threadIdx.x;
    const int kIdx = blockIdx.z % kChunks;
    const int bz = blockIdx.z / kChunks;
    const int kLen = K / kChunks;
    const int kOff = kIdx * kLen;
    const int kTiles = kLen >> 5;   // BK=32; all call sites give kTiles % 4 == 0, >= 8
    const ushort* Ab = A + (long long)bz * sA;
    const ushort* Bb = BT + (long long)bz * sB;

    // XCD-panel swizzle (T1; bijective since gridDim.y % 8 == 0 for all our grids)
    const int W = gridDim.x, H = gridDim.y;
    const int bidx = blockIdx.y * W + blockIdx.x;
    const int Hp = H >> 3;
    const int xcd = bidx & 7;
    const int sb = bidx >> 3;
    const int tn = sb / Hp;
    const int tm = xcd * Hp + sb % Hp;

    const int lane = tid & 63;
    const int w = tid >> 6;    // wave 0..7
    const int wm = w >> 2;     // M half 0..1
    const int wn = w & 3;      // N quarter 0..3
    const int l16 = lane & 15;
    const int quad = lane >> 4;

    // ---- staging: per tile A = 16 KB = 16 x 1KB instr (2/wave), B same.
    // instr covers 16 rows x 32 cols; lane l -> LDS row (l>>2), phys slot (l&3).
    // Source fetches logical slot (l&3) ^ ((lr>>1)&3)  [bank swizzle, R4-verified].
    const int lr = lane >> 2;                                // 0..15
    const int lc = ((lane & 3) ^ ((lane >> 3) & 3)) * 8;     // swizzled source chunk
    const ushort* AgS = Ab + (long long)(tm * 256 + w * 32 + lr) * lda + kOff + lc;
    const ushort* BgS = Bb + (long long)(tn * 256 + w * 32 + lr) * ldb + kOff + lc;
    ushort* AsW = Asl + w * 1024;    // wave's 32 rows within a buf
    ushort* BsW = Bsl + w * 1024;
    const long long rstepA = (long long)16 * lda;
    const long long rstepB = (long long)16 * ldb;

// bfc: buffer index (compile-time in main loop, runtime in tail)
#define STG(tt, bfc) {                                                            \
        const ushort* ga_ = AgS + (tt) * 32; const ushort* gb_ = BgS + (tt) * 32; \
        async_ld16(ga_, AsW + (bfc) * 8192);                                      \
        async_ld16(ga_ + rstepA, AsW + (bfc) * 8192 + 512);                       \
        async_ld16(gb_, BsW + (bfc) * 8192);                                      \
        async_ld16(gb_ + rstepB, BsW + (bfc) * 8192 + 512); }

    // ---- fragment read bases (elem offsets into row-major [256][32] buf)
    // physical slot = quad ^ ((row>>1)&3); row bits 1-2 == l16 bits 1-2.
    const int fsl = (quad ^ ((l16 >> 1) & 3)) * 8;
    const ushort* ArdB = Asl + (wm * 128 + l16) * 32 + fsl;  // + i*512 + bf*8192
    const ushort* BrdB = Bsl + (wn * 64 + l16) * 32 + fsl;   // + j*512 + bf*8192

#define LDF(pre, bfc) {                                                           \
        const ushort* Ar_ = ArdB + (bfc) * 8192;                                  \
        const ushort* Br_ = BrdB + (bfc) * 8192;                                  \
        _Pragma("unroll") for (int i_ = 0; i_ < 8; i_++)                          \
            pre##a[i_] = *(const s16x8*)(Ar_ + i_ * 512);                         \
        _Pragma("unroll") for (int j_ = 0; j_ < 4; j_++)                          \
            pre##b[j_] = *(const s16x8*)(Br_ + j_ * 512); }

#define MM(pre) {                                                                 \
        _Pragma("unroll") for (int i_ = 0; i_ < 8; i_++)                          \
            _Pragma("unroll") for (int j_ = 0; j_ < 2; j_++) {                    \
                acc[i_][2 * j_] = __builtin_amdgcn_mfma_f32_16x16x32_bf16(        \
                    pre##a[i_], pre##b[2 * j_], acc[i_][2 * j_], 0, 0, 0);        \
                acc[i_][2 * j_ + 1] = __builtin_amdgcn_mfma_f32_16x16x32_bf16(    \
                    pre##a[i_], pre##b[2 * j_ + 1], acc[i_][2 * j_ + 1], 0, 0, 0);\
            } }

    f32x4 acc[8][4];
#pragma unroll
    for (int i = 0; i < 8; i++)
#pragma unroll
        for (int j = 0; j < 4; j++) acc[i][j] = (f32x4){0.f, 0.f, 0.f, 0.f};

    s16x8 fca[8], fna[8];
    s16x8 fcb[4], fnb[4];

    // ---- prologue: stage tiles 0,1,2; publish 0,1; prefetch frags(0)
    STG(0, 0); STG(1, 1); STG(2, 2);
    __builtin_amdgcn_s_waitcnt(WAITCNT_VM4);   // tiles 0,1 landed; tile 2 in flight
    __builtin_amdgcn_s_barrier();              // publish 0,1
    LDF(fc, 0);

    // ---- steady state, 4x unrolled: t is a multiple of 4, buffer indices constant.
    // body(t+k): LDF frags(t+k+1) <- buf (k+1)&3 ; STG tile(t+k+3) -> buf (k+3)&3 ;
    //            lgkm12 (frags(t+k) landed) ; MFMA ; vm4 ; barrier (publish t+k+2).
    int t = 0;
    for (; t + 8 <= kTiles; t += 4) {
        LDF(fn, 1); STG(t + 3, 3);
        __builtin_amdgcn_s_waitcnt(WAITCNT_LGKM12);
        MM(fc);
        __builtin_amdgcn_s_waitcnt(WAITCNT_VM4);
        __builtin_amdgcn_s_barrier();

        LDF(fc, 2); STG(t + 4, 0);
        __builtin_amdgcn_s_waitcnt(WAITCNT_LGKM12);
        MM(fn);
        __builtin_amdgcn_s_waitcnt(WAITCNT_VM4);
        __builtin_amdgcn_s_barrier();

        LDF(fn, 3); STG(t + 5, 1);
        __builtin_amdgcn_s_waitcnt(WAITCNT_LGKM12);
        MM(fc);
        __builtin_amdgcn_s_waitcnt(WAITCNT_VM4);
        __builtin_amdgcn_s_barrier();

        LDF(fc, 0); STG(t + 6, 2);
        __builtin_amdgcn_s_waitcnt(WAITCNT_LGKM12);
        MM(fn);
        __builtin_amdgcn_s_waitcnt(WAITCNT_VM4);
        __builtin_amdgcn_s_barrier();
    }

    // ---- guarded tail (<= 8 tiles), runtime buffer indices
    for (; t < kTiles; t += 2) {
        if (t + 1 < kTiles) LDF(fn, (t + 1) & 3);
        if (t + 3 < kTiles) STG(t + 3, (t + 3) & 3);
        if (t + 1 < kTiles) __builtin_amdgcn_s_waitcnt(WAITCNT_LGKM12);
        else                __builtin_amdgcn_s_waitcnt(WAITCNT_LGKM0);
        MM(fc);
        if (t + 2 < kTiles) {
            if (t + 3 < kTiles) __builtin_amdgcn_s_waitcnt(WAITCNT_VM4);
            else                __builtin_amdgcn_s_waitcnt(WAITCNT_VM0);
            __builtin_amdgcn_s_barrier();
        }
        if (t + 1 < kTiles) {
            if (t + 2 < kTiles) LDF(fc, (t + 2) & 3);
            if (t + 4 < kTiles) STG(t + 4, (t + 4) & 3);
            if (t + 2 < kTiles) __builtin_amdgcn_s_waitcnt(WAITCNT_LGKM12);
            else                __builtin_amdgcn_s_waitcnt(WAITCNT_LGKM0);
            MM(fn);
            if (t + 3 < kTiles) {
                if (t + 4 < kTiles) __builtin_amdgcn_s_waitcnt(WAITCNT_VM4);
                else                __builtin_amdgcn_s_waitcnt(WAITCNT_VM0);
                __builtin_amdgcn_s_barrier();
            }
        }
    }
#undef STG
#undef LDF
#undef MM

    __builtin_amdgcn_s_barrier();  // all waves' frag reads retired before C-staging

    // ---- epilogue: acc C/D layout col = lane&15, row = quad*4 + reg [m89/m91].
    // Stage into LDS (group-XOR ^quad -> conflict-free writes; full-row reads),
    // then fully-coalesced global stores (R2-verified: WRITE_SIZE == logical).
    const long long cb = (long long)bz * sC + (long long)kIdx * sK;
    if (OUT_BF16) {
        ushort* Cb = (ushort*)Cp;
        // stage: SH as [256 rows][16 groups of 16 ushorts], group ^= quad
#pragma unroll
        for (int j = 0; j < 4; j++) {
            const int cg = wn * 4 + j;  // col group (col>>4), uniform per wave
            const float bv = HAS_BIAS ? bias[tn * 256 + cg * 16 + l16] : 0.0f;
#pragma unroll
            for (int i = 0; i < 8; i++) {
                const int rbase = wm * 128 + i * 16 + quad * 4;
#pragma unroll
                for (int r = 0; r < 4; r++) {
                    const int row = rbase + r;
                    float v = acc[i][j][r] * scale + bv;
                    if (RELU) v = v > 0.f ? v : 0.f;
                    SH[row * 256 + ((cg ^ ((row >> 2) & 3)) << 4) + l16] = f2b(v);
                }
            }
        }
        __builtin_amdgcn_s_barrier();
        // readout: 16 passes x (16 rows x 32 chunks of 16B); 512B contiguous/row
        const int crow = tid >> 5;  // 0..15
        const int cch = tid & 31;   // 0..31
        const int g = cch >> 1, hh = cch & 1;
#pragma unroll
        for (int pass = 0; pass < 16; pass++) {
            const int row = pass * 16 + crow;
            s16x8 vv = *(const s16x8*)&SH[row * 256 + ((g ^ ((row >> 2) & 3)) << 4) + hh * 8];
            *(s16x8*)&Cb[cb + (long long)(tm * 256 + row) * ldc + tn * 256 + cch * 8] = vv;
        }
    } else {
        float* Cf = (float*)Cp;
        float* SHf = (float*)SH;  // [128 rows][32 groups of 8 floats] per half-pass
#pragma unroll
        for (int half = 0; half < 2; half++) {
            if (wm == half) {
#pragma unroll
                for (int j = 0; j < 4; j++) {
                    const int col = wn * 64 + j * 16 + l16;
                    const float bv = (HAS_BIAS && kIdx == 0) ? bias[tn * 256 + col] : 0.0f;
                    const int gg = col >> 3, cl = col & 7;
#pragma unroll
                    for (int i = 0; i < 8; i++) {
                        const int rbase = i * 16 + quad * 4;  // row within half
#pragma unroll
                        for (int r = 0; r < 4; r++) {
                            const int row = rbase + r;
                            float v = acc[i][j][r] * scale + bv;
                            if (RELU) v = v > 0.f ? v : 0.f;
                            SHf[row * 256 + ((gg ^ ((row >> 2) & 3)) << 3) + cl] = v;
                        }
                    }
                }
            }
            __builtin_amdgcn_s_barrier();
            // readout: 16 passes x (8 rows x 64 chunks of 16B); 1024B contiguous/row
            const int rr = tid >> 6, cc = tid & 63;
            const int g2 = cc >> 1, h2 = cc & 1;
#pragma unroll
            for (int pass = 0; pass < 16; pass++) {
                const int row = pass * 8 + rr;
                f32x4 vv = *(const f32x4*)&SHf[row * 256 + ((g2 ^ ((row >> 2) & 3)) << 3) + h2 * 4];
                *(f32x4*)&Cf[cb + (long long)(tm * 256 + half * 128 + row) * ldc + tn * 256 + cc * 4] = vv;
            }
            __builtin_amdgcn_s_barrier();
        }
    }
}

// ---------------- row softmax: bf16 [rows][2048] -> bf16, vectorized 8/thread -------

__global__ __launch_bounds__(256) void softmax_rows(const ushort* __restrict__ S,
                                                    ushort* __restrict__ P) {
    const int C = 2048;
    const long long row = blockIdx.x;
    const int tid = threadIdx.x;
    const ushort4* s4 = (const ushort4*)(S + row * C) + tid * 2;  // 8 contiguous elems
    ushort4 a = s4[0], bq = s4[1];
    float v[8];
    v[0] = b2f(a.x); v[1] = b2f(a.y); v[2] = b2f(a.z); v[3] = b2f(a.w);
    v[4] = b2f(bq.x); v[5] = b2f(bq.y); v[6] = b2f(bq.z); v[7] = b2f(bq.w);
    float mx = -1e30f;
#pragma unroll
    for (int i = 0; i < 8; i++) mx = fmaxf(mx, v[i]);
    __shared__ float red[256];
    red[tid] = mx;
    __syncthreads();
    for (int off = 128; off > 0; off >>= 1) {
        if (tid < off) red[tid] = fmaxf(red[tid], red[tid + off]);
        __syncthreads();
    }
    mx = red[0];
    __syncthreads();
    float sum = 0.f;
#pragma unroll
    for (int i = 0; i < 8; i++) {
        v[i] = __expf(v[i] - mx);
        sum += v[i];
    }
    red[tid] = sum;
    __syncthreads();
    for (int off = 128; off > 0; off >>= 1) {
        if (tid < off) red[tid] += red[tid + off];
        __syncthreads();
    }
    float inv = 1.f / red[0];
    ushort4 o0, o1;
    o0.x = f2b(v[0] * inv); o0.y = f2b(v[1] * inv); o0.z = f2b(v[2] * inv); o0.w = f2b(v[3] * inv);
    o1.x = f2b(v[4] * inv); o1.y = f2b(v[5] * inv); o1.z = f2b(v[6] * inv); o1.w = f2b(v[7] * inv);
    ushort4* p4 = (ushort4*)(P + row * C) + tid * 2;
    p4[0] = o0;
    p4[1] = o1;
}

// ---------------- fused residual(+partial-sum) + LayerNorm (D=1024) ----------------
// out = LN(X + Y + (Y2?)) ; Y2 nullable (split-K partial reduction fused here).

__global__ __launch_bounds__(256) void residual_ln(const float* __restrict__ X,
                                                   const float* __restrict__ Y,
                                                   const float* __restrict__ Y2,
                                                   const float* __restrict__ g,
                                                   const float* __restrict__ be,
                                                   float* __restrict__ outf,
                                                   ushort* __restrict__ outb) {
    const int D = 1024;
    const long long row = blockIdx.x;
    const float* x = X + row * D;
    const float* y = Y + row * D;
    const float* y2 = Y2 ? Y2 + row * D : nullptr;
    const int tid = threadIdx.x;
    float v[4];
    float s = 0.f, s2 = 0.f;
#pragma unroll
    for (int i = 0; i < 4; i++) {
        int c = tid + i * 256;
        float t = x[c] + y[c];
        if (y2) t += y2[c];
        v[i] = t;
        s += t;
        s2 += t * t;
    }
    __shared__ float r1[256], r2[256];
    r1[tid] = s;
    r2[tid] = s2;
    __syncthreads();
    for (int off = 128; off > 0; off >>= 1) {
        if (tid < off) {
            r1[tid] += r1[tid + off];
            r2[tid] += r2[tid + off];
        }
        __syncthreads();
    }
    float mu = r1[0] * (1.f / 1024.f);
    float var = r2[0] * (1.f / 1024.f) - mu * mu;
    float inv = rsqrtf(var + 1e-5f);
    float* of = outf + row * D;
    ushort* ob = outb ? outb + row * D : nullptr;
#pragma unroll
    for (int i = 0; i < 4; i++) {
        int c = tid + i * 256;
        float o = (v[i] - mu) * inv * g[c] + be[c];
        of[c] = o;
        if (ob) ob[c] = f2b(o);
    }
}

// ---------------- launch ----------------

extern "C" void kernel_launch(void* const* d_in, const int* in_sizes, int n_in,
                              void* d_out, int out_size, void* d_ws, size_t ws_size,
                              hipStream_t stream) {
    const float* x  = (const float*)d_in[0];
    const float* wq = (const float*)d_in[1];
    const float* bq = (const float*)d_in[2];
    const float* wk = (const float*)d_in[3];
    const float* bk = (const float*)d_in[4];
    const float* wv = (const float*)d_in[5];
    const float* bv = (const float*)d_in[6];
    const float* wo = (const float*)d_in[7];
    const float* bo = (const float*)d_in[8];
    const float* w1 = (const float*)d_in[9];
    const float* b1 = (const float*)d_in[10];
    const float* w2 = (const float*)d_in[11];
    const float* b2 = (const float*)d_in[12];
    const float* g1 = (const float*)d_in[13];
    const float* be1 = (const float*)d_in[14];
    const float* g2 = (const float*)d_in[15];
    const float* be2 = (const float*)d_in[16];
    float* out = (float*)d_out;
    char* ws = (char*)d_ws;

    const int Bz = 4, S = 2048, D = 1024, F = 4096;
    const int T = Bz * S;  // 8192 rows
    const size_t MBy = 1024ull * 1024ull;

    // workspace layout (byte offsets), lifetime-based reuse; peak 201 MB
    ushort* qkvT = (ushort*)(ws + 0);        // 6 MB  [3072][1024]; woT follows contiguously
    ushort* woT  = (ushort*)(ws + 6 * MBy);  // 2 MB
    ushort* w1T  = (ushort*)(ws + 8 * MBy);  // 8 MB   [F][D]
    ushort* w2T  = (ushort*)(ws + 16 * MBy); // 8 MB   [D][F]
    float*  bqkv = (float*)(ws + 24 * MBy);  // 12 KB  (dead after QKV gemm)
    ushort* xb   = (ushort*)(ws + 25 * MBy); // 16 MB  (dead after QKV gemm)
    ushort* qkv  = (ushort*)(ws + 41 * MBy); // 48 MB  [T][3072] (dead after scores+vT)
    ushort* vT   = (ushort*)(ws + 89 * MBy); // 16 MB  [B][D][S] (dead after ctx)
    ushort* scb  = (ushort*)(ws + 105 * MBy); // 32 MB bf16 scores (dead after softmax)
    ushort* attn = (ushort*)(ws + 169 * MBy); // 32 MB (dead after ctx)
    // reuse (non-overlapping lifetimes):
    float*  ctx0 = (float*)(ws + 105 * MBy); // 32 MB over scb (dead after add2_cast)
    float*  ctx1 = (float*)(ws + 137 * MBy); // 32 MB (dead after add2_cast)
    ushort* ctxb = (ushort*)(ws + 25 * MBy); // 16 MB over xb (dead after wo)
    float*  ao0 = (float*)(ws + 105 * MBy);  // 32 MB over ctx0 (dead after ln1)
    float*  ao1 = (float*)(ws + 137 * MBy);  // 32 MB (dead after ln1)
    float*  x1  = (float*)(ws + 41 * MBy);   // 32 MB over qkv (live to ln2)
    ushort* x1b = (ushort*)(ws + 73 * MBy);  // 16 MB over qkv (dead after ffn1)
    ushort* h   = (ushort*)(ws + 105 * MBy); // 64 MB over ao (after ln1)
    float*  ff0 = (float*)(ws + 169 * MBy);  // 32 MB over attn
    float*  ff1 = (float*)(ws + 73 * MBy);   // 32 MB over x1b+vT (both dead by ffn2)

    dim3 b32(32, 8);

    // 1) cast x -> bf16
    cast_f2b4<<<(T * D) / 1024, 256, 0, stream>>>(x, xb, (long long)(T * D) / 4);

    // 2) transpose-cast weights: wq/wk/wv/wo -> [qkvT|woT] in ONE dispatch; w1, w2
    transpose4_to_bf16<<<dim3(32, 32, 4), b32, 0, stream>>>(wq, wk, wv, wo, qkvT);
    transpose_to_bf16<float><<<dim3(128, 32, 1), b32, 0, stream>>>(w1, w1T, D, F, F, 0, 0);
    transpose_to_bf16<float><<<dim3(32, 128, 1), b32, 0, stream>>>(w2, w2T, F, D, D, 0, 0);

    // 3) fused bias vector [bq|bk|bv]
    concat3<<<12, 256, 0, stream>>>(bq, bk, bv, bqkv);

    // 4) fused QKV projection: [T][1024] x [3072][1024]^T -> [T][3072] bf16 (384 blocks)
    gemm256<1, 0, 1><<<dim3(3 * D / 256, T / 256, 1), 512, 0, stream>>>(
        xb, qkvT, qkv, bqkv, D, 1, 1.f, D, D, 3 * D, 0, 0, 0, 0);

    // 5) V^T per batch: qkv v-slice [S][1024] (ld 3072) -> [D][S]
    transpose_to_bf16<ushort><<<dim3(D / 32, S / 32, Bz), b32, 0, stream>>>(
        qkv + 2048, vT, S, D, 3 * D, (long long)S * 3 * D, (long long)S * D);

    // 6) scores = Q K^T / 32 -> bf16; A=q, B=k slices of qkv (ld 3072) (256 blocks)
    gemm256<1, 0, 0><<<dim3(S / 256, S / 256, Bz), 512, 0, stream>>>(
        qkv, qkv + 1024, scb, nullptr, D, 1, 0.03125f, 3 * D, 3 * D, S,
        (long long)S * 3 * D, (long long)S * 3 * D, (long long)S * S, 0);

    // 7) softmax rows -> bf16 attn
    softmax_rows<<<T, 256, 0, stream>>>(scb, attn);

    // 8) ctx partials = attn @ V (BT = V^T [D][S]), split-K=2 -> fp32 (256 blocks)
    gemm256<0, 0, 0><<<dim3(D / 256, S / 256, Bz * 2), 512, 0, stream>>>(
        attn, vT, ctx0, nullptr, S, 2, 1.f, S, S, D,
        (long long)S * S, (long long)D * S, (long long)S * D, (long long)(ctx1 - ctx0));

    // 8b) ctx = ctx0 + ctx1 -> bf16
    add2_cast<<<(T * D) / 1024, 256, 0, stream>>>(ctx0, ctx1, ctxb, (long long)(T * D) / 4);

    // 9) attn_out partials = ctx @ wo^T (+bo chunk 0), split-K=2 (256 blocks)
    gemm256<0, 0, 1><<<dim3(D / 256, T / 256, 2), 512, 0, stream>>>(
        ctxb, woT, ao0, bo, D, 2, 1.f, D, D, D, 0, 0, 0, (long long)(ao1 - ao0));

    // 10) x1 = LN(x + ao0 + ao1) -> fp32 + bf16 (split-K reduction fused)
    residual_ln<<<T, 256, 0, stream>>>(x, ao0, ao1, g1, be1, x1, x1b);

    // 11) h = relu(x1 @ w1 + b1) (bf16, 512 blocks)
    gemm256<1, 1, 1><<<dim3(F / 256, T / 256, 1), 512, 0, stream>>>(
        x1b, w1T, h, b1, D, 1, 1.f, D, D, F, 0, 0, 0, 0);

    // 12) ff partials = h @ w2 (+b2 on chunk 0), split-K=2 (256 blocks)
    gemm256<0, 0, 1><<<dim3(D / 256, T / 256, 2), 512, 0, stream>>>(
        h, w2T, ff0, b2, F, 2, 1.f, F, F, D, 0, 0, 0, (long long)(ff1 - ff0));

    // 13) out = LN(x1 + ff0 + ff1) -> d_out fp32 (split-K reduction fused)
    residual_ln<<<T, 256, 0, stream>>>(x1, ff0, ff1, g2, be2, out, nullptr);
}

// Round 6
// 553.410 us; speedup vs baseline: 1.0404x; 1.0162x over previous
//
#include <hip/hip_runtime.h>
#include <stdint.h>

// ---------------- common helpers ----------------

using f32x4 = __attribute__((ext_vector_type(4))) float;
using s16x8 = __attribute__((ext_vector_type(8))) short;

__device__ __forceinline__ ushort f2b(float f) {
    union { float f; uint32_t u; } v; v.f = f;
    uint32_t u = v.u;
    return (ushort)((u + 0x7fffu + ((u >> 16) & 1u)) >> 16);
}
__device__ __forceinline__ float b2f(ushort b) {
    union { uint32_t u; float f; } v; v.u = ((uint32_t)b) << 16;
    return v.f;
}
__device__ __forceinline__ float to_f(float f) { return f; }
__device__ __forceinline__ float to_f(ushort b) { return b2f(b); }

// async global->LDS, 16B per lane; LDS dest = wave-uniform base + lane*16
__device__ __forceinline__ void async_ld16(const ushort* g, ushort* l) {
    __builtin_amdgcn_global_load_lds(
        (const __attribute__((address_space(1))) void*)g,
        (__attribute__((address_space(3))) void*)l,
        16, 0, 0);
}

// s_waitcnt immediates (gfx9): vmcnt[3:0]|[15:14], expcnt[6:4], lgkmcnt[11:8]
#define WAITCNT_VM4    0x0F74  // vmcnt=4, lgkm/exp no-wait
#define WAITCNT_VM0    0x0F70  // vmcnt=0
#define WAITCNT_LGKM0  0xC07F  // lgkmcnt=0, vmcnt/exp no-wait

// ---------------- cast fp32 -> bf16 (vectorized x4) ----------------

__global__ __launch_bounds__(256) void cast_f2b4(const float* __restrict__ src,
                                                 ushort* __restrict__ dst,
                                                 long long n4) {
    long long i = (long long)blockIdx.x * 256 + threadIdx.x;
    if (i >= n4) return;
    float4 f = ((const float4*)src)[i];
    ushort4 o;
    o.x = f2b(f.x); o.y = f2b(f.y); o.z = f2b(f.z); o.w = f2b(f.w);
    ((ushort4*)dst)[i] = o;
}

// ---------------- bias concat: [bq|bk|bv] -> dst (3*1024 floats) ----------------

__global__ __launch_bounds__(256) void concat3(const float* __restrict__ a,
                                               const float* __restrict__ b,
                                               const float* __restrict__ c,
                                               float* __restrict__ dst) {
    int i = blockIdx.x * 256 + threadIdx.x;  // grid 12 blocks = 3072
    const float* s = (i < 1024) ? a : (i < 2048) ? b : c;
    dst[i] = s[i & 1023];
}

// ---------------- split-K partial reduce + cast to bf16 --------------------------

__global__ __launch_bounds__(256) void add2_cast(const float* __restrict__ a,
                                                 const float* __restrict__ b,
                                                 ushort* __restrict__ o,
                                                 long long n4) {
    long long i = (long long)blockIdx.x * 256 + threadIdx.x;
    if (i >= n4) return;
    float4 x = ((const float4*)a)[i];
    float4 y = ((const float4*)b)[i];
    ushort4 u;
    u.x = f2b(x.x + y.x); u.y = f2b(x.y + y.y);
    u.z = f2b(x.z + y.z); u.w = f2b(x.w + y.w);
    ((ushort4*)o)[i] = u;
}

// ---------------- transpose (fp32 or bf16 in) -> bf16 out ----------------
// src: [R][C] with row stride srcLd, dst: [C][R] row-major.
// Grid: (C/32, R/32, batch), block (32,8).

template <typename T>
__global__ __launch_bounds__(256) void transpose_to_bf16(const T* __restrict__ src,
                                                         ushort* __restrict__ dst,
                                                         int R, int C, int srcLd,
                                                         long long ss, long long ds) {
    __shared__ float tile[32][33];
    src += (long long)blockIdx.z * ss;
    dst += (long long)blockIdx.z * ds;
    const int c0 = blockIdx.x * 32;
    const int r0 = blockIdx.y * 32;
    const int tx = threadIdx.x, ty = threadIdx.y;
#pragma unroll
    for (int i = 0; i < 4; i++) {
        int r = r0 + ty + i * 8;
        tile[ty + i * 8][tx] = to_f(src[(long long)r * srcLd + c0 + tx]);
    }
    __syncthreads();
#pragma unroll
    for (int i = 0; i < 4; i++) {
        int r = c0 + ty + i * 8;  // row of dst, in [0, C)
        dst[(long long)r * R + r0 + tx] = f2b(tile[tx][ty + i * 8]);
    }
}

// ---- fused 4x (1024x1024) transpose-cast: z selects {wq,wk,wv,wo}, dst contiguous ----

__global__ __launch_bounds__(256) void transpose4_to_bf16(const float* __restrict__ s0,
                                                          const float* __restrict__ s1,
                                                          const float* __restrict__ s2,
                                                          const float* __restrict__ s3,
                                                          ushort* __restrict__ dst) {
    __shared__ float tile[32][33];
    const int D = 1024;
    const int z = blockIdx.z;
    const float* src = (z == 0) ? s0 : (z == 1) ? s1 : (z == 2) ? s2 : s3;
    dst += (long long)z * D * D;
    const int c0 = blockIdx.x * 32;
    const int r0 = blockIdx.y * 32;
    const int tx = threadIdx.x, ty = threadIdx.y;
#pragma unroll
    for (int i = 0; i < 4; i++) {
        int r = r0 + ty + i * 8;
        tile[ty + i * 8][tx] = src[(long long)r * D + c0 + tx];
    }
    __syncthreads();
#pragma unroll
    for (int i = 0; i < 4; i++) {
        int r = c0 + ty + i * 8;
        dst[(long long)r * D + r0 + tx] = f2b(tile[tx][ty + i * 8]);
    }
}

// ---------------- bf16 MFMA GEMM, 256x256 tile, m201-faithful 8-phase ------------
// C[M,N] = A[M,K] * BT[N,K]^T (+bias, relu, scale). 512 threads = 8 waves (2M x 4N),
// per-wave 128x64 output = acc[8][4] f32x4. LDS: 4 x 32KB BK=32 bufs; a PAIR of
// bufs = one logical BK=64 tile (sub0, sub1). Bank swizzle phys_slot =
// log_slot ^ ((row>>1)&3) on both sides (R4-verified: SQ_LDS_BANK_CONFLICT = 0).
//
// R6 (R3-R5 post-mortems: one-barrier-per-tile "2-phase-class" loop pinned at
// ~2900 cyc/tile = 36% MfmaUtil after falsifying write-amp/conflicts/sched-pin/
// addr-VALU): port the m201 8-phase discipline faithfully (T3+T4 = +28-41%, and
// the prerequisite for T5's +21-25%, per m196/m218/m218b). Per pair (2 K-tiles),
// 4 phases, each exactly:
//   {ds_reads (8 or 4 b128) ; stage 1 unit (2 global_load_lds) ; barrier ;
//    lgkmcnt(0) ; setprio(1) ; 16 MFMA ; setprio(0) ; barrier}
// reads 8/4/8/4 per phase (a[0..3]+b / a[4..7] / same sub1), zero re-reads.
// Counted vmcnt(4) ONLY at phases 2 and 4 (FIFO-verified: ph2-end drains this
// pair's sub1 stage unit, ph4-end drains next pair's sub0 unit; never vm0 in
// steady state). Stage stream: pair t phases 1-4 stage pair t+1's units
// {A-sub0, B-sub0, A-sub1, B-sub1} into the complementary buf pair (free since
// pair t-1's reads lgkm-retired two barriers ago). Last pair: no stages, vm0@ph2.
// Epilogue: R2's LDS-staged coalesced C-write (verified WRITE_SIZE == logical).
// Split-K (kChunks>1): chunk kIdx writes partials at C + kIdx*sK; bias chunk 0 only.

template <int OUT_BF16, int RELU, int HAS_BIAS>
__global__ __launch_bounds__(512, 2) void gemm256(const ushort* __restrict__ A,
                                                  const ushort* __restrict__ BT,
                                                  void* __restrict__ Cp,
                                                  const float* __restrict__ bias,
                                                  int K, int kChunks, float scale,
                                                  int lda, int ldb, int ldc,
                                                  long long sA, long long sB,
                                                  long long sC, long long sK) {
    __shared__ ushort SH[65536];   // 128 KB: A bufs [4][256][32] @0, B bufs @+32768 elems
    ushort* Asl = SH;
    ushort* Bsl = SH + 32768;

    const int tid = threadIdx.x;
    const int kIdx = blockIdx.z % kChunks;
    const int bz = blockIdx.z / kChunks;
    const int kLen = K / kChunks;
    const int kOff = kIdx * kLen;
    const int kTiles = kLen >> 5;   // BK=32; call sites give kTiles in {16,32,64}
    const ushort* Ab = A + (long long)bz * sA;
    const ushort* Bb = BT + (long long)bz * sB;

    // XCD-panel swizzle (T1; bijective since gridDim.y % 8 == 0 for all our grids)
    const int W = gridDim.x, H = gridDim.y;
    const int bidx = blockIdx.y * W + blockIdx.x;
    const int Hp = H >> 3;
    const int xcd = bidx & 7;
    const int sb = bidx >> 3;
    const int tn = sb / Hp;
    const int tm = xcd * Hp + sb % Hp;

    const int lane = tid & 63;
    const int w = tid >> 6;    // wave 0..7
    const int wm = w >> 2;     // M half 0..1
    const int wn = w & 3;      // N quarter 0..3
    const int l16 = lane & 15;
    const int quad = lane >> 4;

    // ---- staging: one K32-tile unit = A 16KB (2 gloads/wave) or B 16KB.
    // instr covers 16 rows x 32 cols; lane l -> LDS row (l>>2), phys slot (l&3).
    // Source fetches logical slot (l&3) ^ ((lr>>1)&3)  [bank swizzle, R4-verified].
    const int lr = lane >> 2;                                // 0..15
    const int lc = ((lane & 3) ^ ((lane >> 3) & 3)) * 8;     // swizzled source chunk
    const ushort* AgS = Ab + (long long)(tm * 256 + w * 32 + lr) * lda + kOff + lc;
    const ushort* BgS = Bb + (long long)(tn * 256 + w * 32 + lr) * ldb + kOff + lc;
    ushort* AsW = Asl + w * 1024;    // wave's 32 rows within a buf
    ushort* BsW = Bsl + w * 1024;
    const long long rstepA = (long long)16 * lda;
    const long long rstepB = (long long)16 * ldb;

#define STG_AU(tt, boff) { const ushort* ga_ = AgS + (tt) * 32;                   \
        async_ld16(ga_, AsW + (boff));                                            \
        async_ld16(ga_ + rstepA, AsW + (boff) + 512); }
#define STG_BU(tt, boff) { const ushort* gb_ = BgS + (tt) * 32;                   \
        async_ld16(gb_, BsW + (boff));                                            \
        async_ld16(gb_ + rstepB, BsW + (boff) + 512); }

    // ---- fragment read bases (elem offsets into row-major [256][32] buf)
    // physical slot = quad ^ ((row>>1)&3); row bits 1-2 == l16 bits 1-2.
    const int fsl = (quad ^ ((l16 >> 1) & 3)) * 8;
    const ushort* ArdB = Asl + (wm * 128 + l16) * 32 + fsl;  // + i*512 + bufoff
    const ushort* BrdB = Bsl + (wn * 64 + l16) * 32 + fsl;   // + j*512 + bufoff

#define LDA4(dst, boff, ib) {                                                     \
    _Pragma("unroll") for (int i_ = 0; i_ < 4; i_++)                              \
        dst[i_] = *(const s16x8*)(ArdB + (boff) + ((ib) + i_) * 512); }
#define LDB4(boff) {                                                              \
    _Pragma("unroll") for (int j_ = 0; j_ < 4; j_++)                              \
        fb[j_] = *(const s16x8*)(BrdB + (boff) + j_ * 512); }
#define MM16(asrc, io) {                                                          \
    _Pragma("unroll") for (int i_ = 0; i_ < 4; i_++)                              \
    _Pragma("unroll") for (int j_ = 0; j_ < 4; j_++)                              \
        acc[(io) + i_][j_] = __builtin_amdgcn_mfma_f32_16x16x32_bf16(             \
            asrc[i_], fb[j_], acc[(io) + i_][j_], 0, 0, 0); }

#define BAR   __builtin_amdgcn_s_barrier()
#define PRIO1 __builtin_amdgcn_s_setprio(1)
#define PRIO0 __builtin_amdgcn_s_setprio(0)
#define WVM4  __builtin_amdgcn_s_waitcnt(WAITCNT_VM4)
#define WVM0  __builtin_amdgcn_s_waitcnt(WAITCNT_VM0)
#define WLG0  __builtin_amdgcn_s_waitcnt(WAITCNT_LGKM0)

// One pair = tiles (sub0 in buf c0, sub1 in buf c1); stages next pair's units
// into bufs d0,d1 (tiles t2=2t+2, t3=2t+3). LAST pair: no stages, vm0 at ph2.
#define PAIR(c0, c1, d0, d1, t2, t3, LAST) {                                      \
    /* ph1: a[0..3] + b of sub0 ; stage A-sub0(next) */                           \
    LDA4(fa, c0, 0); LDB4(c0);                                                    \
    if (!(LAST)) STG_AU(t2, d0);                                                  \
    BAR; WLG0; PRIO1; MM16(fa, 0); PRIO0; BAR;                                    \
    /* ph2: a[4..7] of sub0 ; stage B-sub0(next) ; vm4 drains THIS pair's sub1 */ \
    LDA4(fa2, c0, 4);                                                             \
    if (!(LAST)) STG_BU(t2, d0);                                                  \
    BAR; WLG0; PRIO1; MM16(fa2, 4); PRIO0;                                        \
    if (LAST) { WVM0; } else { WVM4; }                                            \
    BAR;                                                                          \
    /* ph3: a[0..3] + b of sub1 ; stage A-sub1(next) */                           \
    LDA4(fa, c1, 0); LDB4(c1);                                                    \
    if (!(LAST)) STG_AU(t3, d1);                                                  \
    BAR; WLG0; PRIO1; MM16(fa, 0); PRIO0; BAR;                                    \
    /* ph4: a[4..7] of sub1 ; stage B-sub1(next) ; vm4 drains NEXT pair's sub0 */ \
    LDA4(fa2, c1, 4);                                                             \
    if (!(LAST)) STG_BU(t3, d1);                                                  \
    BAR; WLG0; PRIO1; MM16(fa2, 4); PRIO0;                                        \
    if (!(LAST)) { WVM4; }                                                        \
    BAR; }

    f32x4 acc[8][4];
#pragma unroll
    for (int i = 0; i < 8; i++)
#pragma unroll
        for (int j = 0; j < 4; j++) acc[i][j] = (f32x4){0.f, 0.f, 0.f, 0.f};

    s16x8 fa[4], fa2[4], fb[4];

    // ---- prologue: stage pair0 (4 units, 8 loads); vm4 lands sub0, sub1 in flight.
    STG_AU(0, 0); STG_BU(0, 0); STG_AU(1, 8192); STG_BU(1, 8192);
    WVM4;
    BAR;

    // ---- pairs: even pair -> bufs (0,1), odd -> (2,3); nP is even, >= 8.
    const int nP = kTiles >> 1;
    int pr = 0;
    for (; pr + 3 <= nP; pr += 2) {
        PAIR(0, 8192, 16384, 24576, 2 * pr + 2, 2 * pr + 3, 0);
        PAIR(16384, 24576, 0, 8192, 2 * pr + 4, 2 * pr + 5, 0);
    }
    // tail: pair nP-2 (stages the last pair), then last pair (no stages)
    PAIR(0, 8192, 16384, 24576, 2 * pr + 2, 2 * pr + 3, 0);
    PAIR(16384, 24576, 0, 8192, 0, 0, 1);

#undef STG_AU
#undef STG_BU
#undef LDA4
#undef LDB4
#undef MM16
#undef PAIR

    BAR;  // all waves' frag reads retired before C-staging reuses SH

    // ---- epilogue: acc C/D layout col = lane&15, row = quad*4 + reg [m89/m91].
    // Stage into LDS (group-XOR ^quad -> conflict-free writes; full-row reads),
    // then fully-coalesced global stores (R2-verified: WRITE_SIZE == logical).
    const long long cb = (long long)bz * sC + (long long)kIdx * sK;
    if (OUT_BF16) {
        ushort* Cb = (ushort*)Cp;
        // stage: SH as [256 rows][16 groups of 16 ushorts], group ^= quad
#pragma unroll
        for (int j = 0; j < 4; j++) {
            const int cg = wn * 4 + j;  // col group (col>>4), uniform per wave
            const float bv = HAS_BIAS ? bias[tn * 256 + cg * 16 + l16] : 0.0f;
#pragma unroll
            for (int i = 0; i < 8; i++) {
                const int rbase = wm * 128 + i * 16 + quad * 4;
#pragma unroll
                for (int r = 0; r < 4; r++) {
                    const int row = rbase + r;
                    float v = acc[i][j][r] * scale + bv;
                    if (RELU) v = v > 0.f ? v : 0.f;
                    SH[row * 256 + ((cg ^ ((row >> 2) & 3)) << 4) + l16] = f2b(v);
                }
            }
        }
        BAR;
        // readout: 16 passes x (16 rows x 32 chunks of 16B); 512B contiguous/row
        const int crow = tid >> 5;  // 0..15
        const int cch = tid & 31;   // 0..31
        const int g = cch >> 1, hh = cch & 1;
#pragma unroll
        for (int pass = 0; pass < 16; pass++) {
            const int row = pass * 16 + crow;
            s16x8 vv = *(const s16x8*)&SH[row * 256 + ((g ^ ((row >> 2) & 3)) << 4) + hh * 8];
            *(s16x8*)&Cb[cb + (long long)(tm * 256 + row) * ldc + tn * 256 + cch * 8] = vv;
        }
    } else {
        float* Cf = (float*)Cp;
        float* SHf = (float*)SH;  // [128 rows][32 groups of 8 floats] per half-pass
#pragma unroll
        for (int half = 0; half < 2; half++) {
            if (wm == half) {
#pragma unroll
                for (int j = 0; j < 4; j++) {
                    const int col = wn * 64 + j * 16 + l16;
                    const float bv = (HAS_BIAS && kIdx == 0) ? bias[tn * 256 + col] : 0.0f;
                    const int gg = col >> 3, cl = col & 7;
#pragma unroll
                    for (int i = 0; i < 8; i++) {
                        const int rbase = i * 16 + quad * 4;  // row within half
#pragma unroll
                        for (int r = 0; r < 4; r++) {
                            const int row = rbase + r;
                            float v = acc[i][j][r] * scale + bv;
                            if (RELU) v = v > 0.f ? v : 0.f;
                            SHf[row * 256 + ((gg ^ ((row >> 2) & 3)) << 3) + cl] = v;
                        }
                    }
                }
            }
            BAR;
            // readout: 16 passes x (8 rows x 64 chunks of 16B); 1024B contiguous/row
            const int rr = tid >> 6, cc = tid & 63;
            const int g2 = cc >> 1, h2 = cc & 1;
#pragma unroll
            for (int pass = 0; pass < 16; pass++) {
                const int row = pass * 8 + rr;
                f32x4 vv = *(const f32x4*)&SHf[row * 256 + ((g2 ^ ((row >> 2) & 3)) << 3) + h2 * 4];
                *(f32x4*)&Cf[cb + (long long)(tm * 256 + half * 128 + row) * ldc + tn * 256 + cc * 4] = vv;
            }
            BAR;
        }
    }
#undef BAR
#undef PRIO1
#undef PRIO0
#undef WVM4
#undef WVM0
#undef WLG0
}

// ---------------- row softmax: bf16 [rows][2048] -> bf16, vectorized 8/thread -------

__global__ __launch_bounds__(256) void softmax_rows(const ushort* __restrict__ S,
                                                    ushort* __restrict__ P) {
    const int C = 2048;
    const long long row = blockIdx.x;
    const int tid = threadIdx.x;
    const ushort4* s4 = (const ushort4*)(S + row * C) + tid * 2;  // 8 contiguous elems
    ushort4 a = s4[0], bq = s4[1];
    float v[8];
    v[0] = b2f(a.x); v[1] = b2f(a.y); v[2] = b2f(a.z); v[3] = b2f(a.w);
    v[4] = b2f(bq.x); v[5] = b2f(bq.y); v[6] = b2f(bq.z); v[7] = b2f(bq.w);
    float mx = -1e30f;
#pragma unroll
    for (int i = 0; i < 8; i++) mx = fmaxf(mx, v[i]);
    __shared__ float red[256];
    red[tid] = mx;
    __syncthreads();
    for (int off = 128; off > 0; off >>= 1) {
        if (tid < off) red[tid] = fmaxf(red[tid], red[tid + off]);
        __syncthreads();
    }
    mx = red[0];
    __syncthreads();
    float sum = 0.f;
#pragma unroll
    for (int i = 0; i < 8; i++) {
        v[i] = __expf(v[i] - mx);
        sum += v[i];
    }
    red[tid] = sum;
    __syncthreads();
    for (int off = 128; off > 0; off >>= 1) {
        if (tid < off) red[tid] += red[tid + off];
        __syncthreads();
    }
    float inv = 1.f / red[0];
    ushort4 o0, o1;
    o0.x = f2b(v[0] * inv); o0.y = f2b(v[1] * inv); o0.z = f2b(v[2] * inv); o0.w = f2b(v[3] * inv);
    o1.x = f2b(v[4] * inv); o1.y = f2b(v[5] * inv); o1.z = f2b(v[6] * inv); o1.w = f2b(v[7] * inv);
    ushort4* p4 = (ushort4*)(P + row * C) + tid * 2;
    p4[0] = o0;
    p4[1] = o1;
}

// ---------------- fused residual(+partial-sum) + LayerNorm (D=1024) ----------------
// out = LN(X + Y + (Y2?)) ; Y2 nullable (split-K partial reduction fused here).

__global__ __launch_bounds__(256) void residual_ln(const float* __restrict__ X,
                                                   const float* __restrict__ Y,
                                                   const float* __restrict__ Y2,
                                                   const float* __restrict__ g,
                                                   const float* __restrict__ be,
                                                   float* __restrict__ outf,
                                                   ushort* __restrict__ outb) {
    const int D = 1024;
    const long long row = blockIdx.x;
    const float* x = X + row * D;
    const float* y = Y + row * D;
    const float* y2 = Y2 ? Y2 + row * D : nullptr;
    const int tid = threadIdx.x;
    float v[4];
    float s = 0.f, s2 = 0.f;
#pragma unroll
    for (int i = 0; i < 4; i++) {
        int c = tid + i * 256;
        float t = x[c] + y[c];
        if (y2) t += y2[c];
        v[i] = t;
        s += t;
        s2 += t * t;
    }
    __shared__ float r1[256], r2[256];
    r1[tid] = s;
    r2[tid] = s2;
    __syncthreads();
    for (int off = 128; off > 0; off >>= 1) {
        if (tid < off) {
            r1[tid] += r1[tid + off];
            r2[tid] += r2[tid + off];
        }
        __syncthreads();
    }
    float mu = r1[0] * (1.f / 1024.f);
    float var = r2[0] * (1.f / 1024.f) - mu * mu;
    float inv = rsqrtf(var + 1e-5f);
    float* of = outf + row * D;
    ushort* ob = outb ? outb + row * D : nullptr;
#pragma unroll
    for (int i = 0; i < 4; i++) {
        int c = tid + i * 256;
        float o = (v[i] - mu) * inv * g[c] + be[c];
        of[c] = o;
        if (ob) ob[c] = f2b(o);
    }
}

// ---------------- launch ----------------

extern "C" void kernel_launch(void* const* d_in, const int* in_sizes, int n_in,
                              void* d_out, int out_size, void* d_ws, size_t ws_size,
                              hipStream_t stream) {
    const float* x  = (const float*)d_in[0];
    const float* wq = (const float*)d_in[1];
    const float* bq = (const float*)d_in[2];
    const float* wk = (const float*)d_in[3];
    const float* bk = (const float*)d_in[4];
    const float* wv = (const float*)d_in[5];
    const float* bv = (const float*)d_in[6];
    const float* wo = (const float*)d_in[7];
    const float* bo = (const float*)d_in[8];
    const float* w1 = (const float*)d_in[9];
    const float* b1 = (const float*)d_in[10];
    const float* w2 = (const float*)d_in[11];
    const float* b2 = (const float*)d_in[12];
    const float* g1 = (const float*)d_in[13];
    const float* be1 = (const float*)d_in[14];
    const float* g2 = (const float*)d_in[15];
    const float* be2 = (const float*)d_in[16];
    float* out = (float*)d_out;
    char* ws = (char*)d_ws;

    const int Bz = 4, S = 2048, D = 1024, F = 4096;
    const int T = Bz * S;  // 8192 rows
    const size_t MBy = 1024ull * 1024ull;

    // workspace layout (byte offsets), lifetime-based reuse; peak 201 MB
    ushort* qkvT = (ushort*)(ws + 0);        // 6 MB  [3072][1024]; woT follows contiguously
    ushort* woT  = (ushort*)(ws + 6 * MBy);  // 2 MB
    ushort* w1T  = (ushort*)(ws + 8 * MBy);  // 8 MB   [F][D]
    ushort* w2T  = (ushort*)(ws + 16 * MBy); // 8 MB   [D][F]
    float*  bqkv = (float*)(ws + 24 * MBy);  // 12 KB  (dead after QKV gemm)
    ushort* xb   = (ushort*)(ws + 25 * MBy); // 16 MB  (dead after QKV gemm)
    ushort* qkv  = (ushort*)(ws + 41 * MBy); // 48 MB  [T][3072] (dead after scores+vT)
    ushort* vT   = (ushort*)(ws + 89 * MBy); // 16 MB  [B][D][S] (dead after ctx)
    ushort* scb  = (ushort*)(ws + 105 * MBy); // 32 MB bf16 scores (dead after softmax)
    ushort* attn = (ushort*)(ws + 169 * MBy); // 32 MB (dead after ctx)
    // reuse (non-overlapping lifetimes):
    float*  ctx0 = (float*)(ws + 105 * MBy); // 32 MB over scb (dead after add2_cast)
    float*  ctx1 = (float*)(ws + 137 * MBy); // 32 MB (dead after add2_cast)
    ushort* ctxb = (ushort*)(ws + 25 * MBy); // 16 MB over xb (dead after wo)
    float*  ao0 = (float*)(ws + 105 * MBy);  // 32 MB over ctx0 (dead after ln1)
    float*  ao1 = (float*)(ws + 137 * MBy);  // 32 MB (dead after ln1)
    float*  x1  = (float*)(ws + 41 * MBy);   // 32 MB over qkv (live to ln2)
    ushort* x1b = (ushort*)(ws + 73 * MBy);  // 16 MB over qkv (dead after ffn1)
    ushort* h   = (ushort*)(ws + 105 * MBy); // 64 MB over ao (after ln1)
    float*  ff0 = (float*)(ws + 169 * MBy);  // 32 MB over attn
    float*  ff1 = (float*)(ws + 73 * MBy);   // 32 MB over x1b+vT (both dead by ffn2)

    dim3 b32(32, 8);

    // 1) cast x -> bf16
    cast_f2b4<<<(T * D) / 1024, 256, 0, stream>>>(x, xb, (long long)(T * D) / 4);

    // 2) transpose-cast weights: wq/wk/wv/wo -> [qkvT|woT] in ONE dispatch; w1, w2
    transpose4_to_bf16<<<dim3(32, 32, 4), b32, 0, stream>>>(wq, wk, wv, wo, qkvT);
    transpose_to_bf16<float><<<dim3(128, 32, 1), b32, 0, stream>>>(w1, w1T, D, F, F, 0, 0);
    transpose_to_bf16<float><<<dim3(32, 128, 1), b32, 0, stream>>>(w2, w2T, F, D, D, 0, 0);

    // 3) fused bias vector [bq|bk|bv]
    concat3<<<12, 256, 0, stream>>>(bq, bk, bv, bqkv);

    // 4) fused QKV projection: [T][1024] x [3072][1024]^T -> [T][3072] bf16 (384 blocks)
    gemm256<1, 0, 1><<<dim3(3 * D / 256, T / 256, 1), 512, 0, stream>>>(
        xb, qkvT, qkv, bqkv, D, 1, 1.f, D, D, 3 * D, 0, 0, 0, 0);

    // 5) V^T per batch: qkv v-slice [S][1024] (ld 3072) -> [D][S]
    transpose_to_bf16<ushort><<<dim3(D / 32, S / 32, Bz), b32, 0, stream>>>(
        qkv + 2048, vT, S, D, 3 * D, (long long)S * 3 * D, (long long)S * D);

    // 6) scores = Q K^T / 32 -> bf16; A=q, B=k slices of qkv (ld 3072) (256 blocks)
    gemm256<1, 0, 0><<<dim3(S / 256, S / 256, Bz), 512, 0, stream>>>(
        qkv, qkv + 1024, scb, nullptr, D, 1, 0.03125f, 3 * D, 3 * D, S,
        (long long)S * 3 * D, (long long)S * 3 * D, (long long)S * S, 0);

    // 7) softmax rows -> bf16 attn
    softmax_rows<<<T, 256, 0, stream>>>(scb, attn);

    // 8) ctx partials = attn @ V (BT = V^T [D][S]), split-K=2 -> fp32 (256 blocks)
    gemm256<0, 0, 0><<<dim3(D / 256, S / 256, Bz * 2), 512, 0, stream>>>(
        attn, vT, ctx0, nullptr, S, 2, 1.f, S, S, D,
        (long long)S * S, (long long)D * S, (long long)S * D, (long long)(ctx1 - ctx0));

    // 8b) ctx = ctx0 + ctx1 -> bf16
    add2_cast<<<(T * D) / 1024, 256, 0, stream>>>(ctx0, ctx1, ctxb, (long long)(T * D) / 4);

    // 9) attn_out partials = ctx @ wo^T (+bo chunk 0), split-K=2 (256 blocks)
    gemm256<0, 0, 1><<<dim3(D / 256, T / 256, 2), 512, 0, stream>>>(
        ctxb, woT, ao0, bo, D, 2, 1.f, D, D, D, 0, 0, 0, (long long)(ao1 - ao0));

    // 10) x1 = LN(x + ao0 + ao1) -> fp32 + bf16 (split-K reduction fused)
    residual_ln<<<T, 256, 0, stream>>>(x, ao0, ao1, g1, be1, x1, x1b);

    // 11) h = relu(x1 @ w1 + b1) (bf16, 512 blocks)
    gemm256<1, 1, 1><<<dim3(F / 256, T / 256, 1), 512, 0, stream>>>(
        x1b, w1T, h, b1, D, 1, 1.f, D, D, F, 0, 0, 0, 0);

    // 12) ff partials = h @ w2 (+b2 on chunk 0), split-K=2 (256 blocks)
    gemm256<0, 0, 1><<<dim3(D / 256, T / 256, 2), 512, 0, stream>>>(
        h, w2T, ff0, b2, F, 2, 1.f, F, F, D, 0, 0, 0, (long long)(ff1 - ff0));

    // 13) out = LN(x1 + ff0 + ff1) -> d_out fp32 (split-K reduction fused)
    residual_ln<<<T, 256, 0, stream>>>(x1, ff0, ff1, g2, be2, out, nullptr);
}

// Round 7
// 539.050 us; speedup vs baseline: 1.0681x; 1.0266x over previous
//
#include <hip/hip_runtime.h>
#include <stdint.h>

// ---------------- common helpers ----------------

using f32x4 = __attribute__((ext_vector_type(4))) float;
using s16x8 = __attribute__((ext_vector_type(8))) short;

__device__ __forceinline__ ushort f2b(float f) {
    union { float f; uint32_t u; } v; v.f = f;
    uint32_t u = v.u;
    return (ushort)((u + 0x7fffu + ((u >> 16) & 1u)) >> 16);
}
__device__ __forceinline__ float b2f(ushort b) {
    union { uint32_t u; float f; } v; v.u = ((uint32_t)b) << 16;
    return v.f;
}
__device__ __forceinline__ float to_f(float f) { return f; }
__device__ __forceinline__ float to_f(ushort b) { return b2f(b); }

// async global->LDS, 16B per lane; LDS dest = wave-uniform base + lane*16
__device__ __forceinline__ void async_ld16(const ushort* g, ushort* l) {
    __builtin_amdgcn_global_load_lds(
        (const __attribute__((address_space(1))) void*)g,
        (__attribute__((address_space(3))) void*)l,
        16, 0, 0);
}

// s_waitcnt immediates (gfx9): vmcnt[3:0]|[15:14], expcnt[6:4], lgkmcnt[11:8]
#define WAITCNT_VM4    0x0F74  // vmcnt=4, lgkm/exp no-wait
#define WAITCNT_VM0    0x0F70  // vmcnt=0
#define WAITCNT_LGKM0  0xC07F  // lgkmcnt=0, vmcnt/exp no-wait

// ---------------- cast fp32 -> bf16 (vectorized x4) ----------------

__global__ __launch_bounds__(256) void cast_f2b4(const float* __restrict__ src,
                                                 ushort* __restrict__ dst,
                                                 long long n4) {
    long long i = (long long)blockIdx.x * 256 + threadIdx.x;
    if (i >= n4) return;
    float4 f = ((const float4*)src)[i];
    ushort4 o;
    o.x = f2b(f.x); o.y = f2b(f.y); o.z = f2b(f.z); o.w = f2b(f.w);
    ((ushort4*)dst)[i] = o;
}

// ---------------- bias concat: [bq|bk|bv] -> dst (3*1024 floats) ----------------

__global__ __launch_bounds__(256) void concat3(const float* __restrict__ a,
                                               const float* __restrict__ b,
                                               const float* __restrict__ c,
                                               float* __restrict__ dst) {
    int i = blockIdx.x * 256 + threadIdx.x;  // grid 12 blocks = 3072
    const float* s = (i < 1024) ? a : (i < 2048) ? b : c;
    dst[i] = s[i & 1023];
}

// ---------------- split-K partial reduce + cast to bf16 --------------------------

__global__ __launch_bounds__(256) void add2_cast(const float* __restrict__ a,
                                                 const float* __restrict__ b,
                                                 ushort* __restrict__ o,
                                                 long long n4) {
    long long i = (long long)blockIdx.x * 256 + threadIdx.x;
    if (i >= n4) return;
    float4 x = ((const float4*)a)[i];
    float4 y = ((const float4*)b)[i];
    ushort4 u;
    u.x = f2b(x.x + y.x); u.y = f2b(x.y + y.y);
    u.z = f2b(x.z + y.z); u.w = f2b(x.w + y.w);
    ((ushort4*)o)[i] = u;
}

// ---------------- transpose (fp32 or bf16 in) -> bf16 out ----------------
// src: [R][C] with row stride srcLd, dst: [C][R] row-major.
// Grid: (C/32, R/32, batch), block (32,8).

template <typename T>
__global__ __launch_bounds__(256) void transpose_to_bf16(const T* __restrict__ src,
                                                         ushort* __restrict__ dst,
                                                         int R, int C, int srcLd,
                                                         long long ss, long long ds) {
    __shared__ float tile[32][33];
    src += (long long)blockIdx.z * ss;
    dst += (long long)blockIdx.z * ds;
    const int c0 = blockIdx.x * 32;
    const int r0 = blockIdx.y * 32;
    const int tx = threadIdx.x, ty = threadIdx.y;
#pragma unroll
    for (int i = 0; i < 4; i++) {
        int r = r0 + ty + i * 8;
        tile[ty + i * 8][tx] = to_f(src[(long long)r * srcLd + c0 + tx]);
    }
    __syncthreads();
#pragma unroll
    for (int i = 0; i < 4; i++) {
        int r = c0 + ty + i * 8;  // row of dst, in [0, C)
        dst[(long long)r * R + r0 + tx] = f2b(tile[tx][ty + i * 8]);
    }
}

// ---- fused 4x (1024x1024) transpose-cast: z selects {wq,wk,wv,wo}, dst contiguous ----

__global__ __launch_bounds__(256) void transpose4_to_bf16(const float* __restrict__ s0,
                                                          const float* __restrict__ s1,
                                                          const float* __restrict__ s2,
                                                          const float* __restrict__ s3,
                                                          ushort* __restrict__ dst) {
    __shared__ float tile[32][33];
    const int D = 1024;
    const int z = blockIdx.z;
    const float* src = (z == 0) ? s0 : (z == 1) ? s1 : (z == 2) ? s2 : s3;
    dst += (long long)z * D * D;
    const int c0 = blockIdx.x * 32;
    const int r0 = blockIdx.y * 32;
    const int tx = threadIdx.x, ty = threadIdx.y;
#pragma unroll
    for (int i = 0; i < 4; i++) {
        int r = r0 + ty + i * 8;
        tile[ty + i * 8][tx] = src[(long long)r * D + c0 + tx];
    }
    __syncthreads();
#pragma unroll
    for (int i = 0; i < 4; i++) {
        int r = c0 + ty + i * 8;
        dst[(long long)r * D + r0 + tx] = f2b(tile[tx][ty + i * 8]);
    }
}

// ---------------- bf16 MFMA GEMM, 256x256 tile, m201-faithful 8-phase ------------
// C[M,N] = A[M,K] * BT[N,K]^T (+bias, relu, scale). 512 threads = 8 waves (2M x 4N),
// per-wave 128x64 output = acc[8][4] f32x4. LDS: 4 x 32KB BK=32 bufs; a PAIR of
// bufs = one logical BK=64 tile (sub0, sub1). Bank swizzle phys_slot =
// log_slot ^ ((row>>1)&3) on both sides (R4-verified: SQ_LDS_BANK_CONFLICT = 0).
// Phase discipline per R6 (m201-faithful): 4 phases/pair, each {ds_reads; stage 1
// unit; barrier; lgkm0; setprio1; 16 MFMA; setprio0; barrier}; counted vm4 only at
// ph2/ph4; last pair vm0@ph2, no stages.
//
// R7 fix (R6 post-mortem: ~5000 cyc/pair vs 2483 MFMA floor with conflicts=0,
// writes coalesced, waits counted, phases faithful): REGISTER WAR HAZARD. fb[]
// was written by ph1, read by ph1+ph2 MFMAs, then overwritten by ph3's LDB4 right
// after ph2's closing barrier -- while ph2's MFMAs still drain reading fb (same at
// the pair boundary for ph4->ph1'). Whether HW-interlocked or compiler-padded,
// that serializes reads behind ~600 cyc of drain twice per pair. Fix: fb0 (sub0)
// / fb1 (sub1) double-buffer; after the split every register set's writer is >= 1
// full phase after its last reader's issue (fa: ph1 w, last read ph1; ph3 w -- gap
// ph2. fa2: ph2 w, last read ph2? no -- read ph2; next w ph4 -- gap ph3; pair
// boundary gaps >= 1 phase). +16 VGPR, occupancy unchanged.
// Epilogue: R2's LDS-staged coalesced C-write (verified WRITE_SIZE == logical).
// Split-K (kChunks>1): chunk kIdx writes partials at C + kIdx*sK; bias chunk 0 only.

template <int OUT_BF16, int RELU, int HAS_BIAS>
__global__ __launch_bounds__(512, 2) void gemm256(const ushort* __restrict__ A,
                                                  const ushort* __restrict__ BT,
                                                  void* __restrict__ Cp,
                                                  const float* __restrict__ bias,
                                                  int K, int kChunks, float scale,
                                                  int lda, int ldb, int ldc,
                                                  long long sA, long long sB,
                                                  long long sC, long long sK) {
    __shared__ ushort SH[65536];   // 128 KB: A bufs [4][256][32] @0, B bufs @+32768 elems
    ushort* Asl = SH;
    ushort* Bsl = SH + 32768;

    const int tid = threadIdx.x;
    const int kIdx = blockIdx.z % kChunks;
    const int bz = blockIdx.z / kChunks;
    const int kLen = K / kChunks;
    const int kOff = kIdx * kLen;
    const int kTiles = kLen >> 5;   // BK=32; call sites give kTiles in {16,32,64}
    const ushort* Ab = A + (long long)bz * sA;
    const ushort* Bb = BT + (long long)bz * sB;

    // XCD-panel swizzle (T1; bijective since gridDim.y % 8 == 0 for all our grids)
    const int W = gridDim.x, H = gridDim.y;
    const int bidx = blockIdx.y * W + blockIdx.x;
    const int Hp = H >> 3;
    const int xcd = bidx & 7;
    const int sb = bidx >> 3;
    const int tn = sb / Hp;
    const int tm = xcd * Hp + sb % Hp;

    const int lane = tid & 63;
    const int w = tid >> 6;    // wave 0..7
    const int wm = w >> 2;     // M half 0..1
    const int wn = w & 3;      // N quarter 0..3
    const int l16 = lane & 15;
    const int quad = lane >> 4;

    // ---- staging: one K32-tile unit = A 16KB (2 gloads/wave) or B 16KB.
    // instr covers 16 rows x 32 cols; lane l -> LDS row (l>>2), phys slot (l&3).
    // Source fetches logical slot (l&3) ^ ((lr>>1)&3)  [bank swizzle, R4-verified].
    const int lr = lane >> 2;                                // 0..15
    const int lc = ((lane & 3) ^ ((lane >> 3) & 3)) * 8;     // swizzled source chunk
    const ushort* AgS = Ab + (long long)(tm * 256 + w * 32 + lr) * lda + kOff + lc;
    const ushort* BgS = Bb + (long long)(tn * 256 + w * 32 + lr) * ldb + kOff + lc;
    ushort* AsW = Asl + w * 1024;    // wave's 32 rows within a buf
    ushort* BsW = Bsl + w * 1024;
    const long long rstepA = (long long)16 * lda;
    const long long rstepB = (long long)16 * ldb;

#define STG_AU(tt, boff) { const ushort* ga_ = AgS + (tt) * 32;                   \
        async_ld16(ga_, AsW + (boff));                                            \
        async_ld16(ga_ + rstepA, AsW + (boff) + 512); }
#define STG_BU(tt, boff) { const ushort* gb_ = BgS + (tt) * 32;                   \
        async_ld16(gb_, BsW + (boff));                                            \
        async_ld16(gb_ + rstepB, BsW + (boff) + 512); }

    // ---- fragment read bases (elem offsets into row-major [256][32] buf)
    // physical slot = quad ^ ((row>>1)&3); row bits 1-2 == l16 bits 1-2.
    const int fsl = (quad ^ ((l16 >> 1) & 3)) * 8;
    const ushort* ArdB = Asl + (wm * 128 + l16) * 32 + fsl;  // + i*512 + bufoff
    const ushort* BrdB = Bsl + (wn * 64 + l16) * 32 + fsl;   // + j*512 + bufoff

#define LDA4(dst, boff, ib) {                                                     \
    _Pragma("unroll") for (int i_ = 0; i_ < 4; i_++)                              \
        dst[i_] = *(const s16x8*)(ArdB + (boff) + ((ib) + i_) * 512); }
#define LDB4(dst, boff) {                                                         \
    _Pragma("unroll") for (int j_ = 0; j_ < 4; j_++)                              \
        dst[j_] = *(const s16x8*)(BrdB + (boff) + j_ * 512); }
#define MM16(asrc, bsrc, io) {                                                    \
    _Pragma("unroll") for (int i_ = 0; i_ < 4; i_++)                              \
    _Pragma("unroll") for (int j_ = 0; j_ < 4; j_++)                              \
        acc[(io) + i_][j_] = __builtin_amdgcn_mfma_f32_16x16x32_bf16(             \
            asrc[i_], bsrc[j_], acc[(io) + i_][j_], 0, 0, 0); }

#define BAR   __builtin_amdgcn_s_barrier()
#define PRIO1 __builtin_amdgcn_s_setprio(1)
#define PRIO0 __builtin_amdgcn_s_setprio(0)
#define WVM4  __builtin_amdgcn_s_waitcnt(WAITCNT_VM4)
#define WVM0  __builtin_amdgcn_s_waitcnt(WAITCNT_VM0)
#define WLG0  __builtin_amdgcn_s_waitcnt(WAITCNT_LGKM0)

// One pair = tiles (sub0 in buf c0, sub1 in buf c1); stages next pair's units
// into bufs d0,d1 (tiles t2=2t+2, t3=2t+3). LAST pair: no stages, vm0 at ph2.
// Register sets: ph1 {fa,fb0} ph2 {fa2,fb0} ph3 {fa,fb1} ph4 {fa2,fb1} -- no
// phase writes a register set whose MFMA drain is within the previous phase.
#define PAIR(c0, c1, d0, d1, t2, t3, LAST) {                                      \
    /* ph1: a[0..3] + b0 of sub0 ; stage A-sub0(next) */                          \
    LDA4(fa, c0, 0); LDB4(fb0, c0);                                               \
    if (!(LAST)) STG_AU(t2, d0);                                                  \
    BAR; WLG0; PRIO1; MM16(fa, fb0, 0); PRIO0; BAR;                               \
    /* ph2: a[4..7] of sub0 ; stage B-sub0(next) ; vm4 drains THIS pair's sub1 */ \
    LDA4(fa2, c0, 4);                                                             \
    if (!(LAST)) STG_BU(t2, d0);                                                  \
    BAR; WLG0; PRIO1; MM16(fa2, fb0, 4); PRIO0;                                   \
    if (LAST) { WVM0; } else { WVM4; }                                            \
    BAR;                                                                          \
    /* ph3: a[0..3] + b1 of sub1 ; stage A-sub1(next) */                          \
    LDA4(fa, c1, 0); LDB4(fb1, c1);                                               \
    if (!(LAST)) STG_AU(t3, d1);                                                  \
    BAR; WLG0; PRIO1; MM16(fa, fb1, 0); PRIO0; BAR;                               \
    /* ph4: a[4..7] of sub1 ; stage B-sub1(next) ; vm4 drains NEXT pair's sub0 */ \
    LDA4(fa2, c1, 4);                                                             \
    if (!(LAST)) STG_BU(t3, d1);                                                  \
    BAR; WLG0; PRIO1; MM16(fa2, fb1, 4); PRIO0;                                   \
    if (!(LAST)) { WVM4; }                                                        \
    BAR; }

    f32x4 acc[8][4];
#pragma unroll
    for (int i = 0; i < 8; i++)
#pragma unroll
        for (int j = 0; j < 4; j++) acc[i][j] = (f32x4){0.f, 0.f, 0.f, 0.f};

    s16x8 fa[4], fa2[4], fb0[4], fb1[4];

    // ---- prologue: stage pair0 (4 units, 8 loads); vm4 lands sub0, sub1 in flight.
    STG_AU(0, 0); STG_BU(0, 0); STG_AU(1, 8192); STG_BU(1, 8192);
    WVM4;
    BAR;

    // ---- pairs: even pair -> bufs (0,1), odd -> (2,3); nP is even, >= 8.
    const int nP = kTiles >> 1;
    int pr = 0;
    for (; pr + 3 <= nP; pr += 2) {
        PAIR(0, 8192, 16384, 24576, 2 * pr + 2, 2 * pr + 3, 0);
        PAIR(16384, 24576, 0, 8192, 2 * pr + 4, 2 * pr + 5, 0);
    }
    // tail: pair nP-2 (stages the last pair), then last pair (no stages)
    PAIR(0, 8192, 16384, 24576, 2 * pr + 2, 2 * pr + 3, 0);
    PAIR(16384, 24576, 0, 8192, 0, 0, 1);

#undef STG_AU
#undef STG_BU
#undef LDA4
#undef LDB4
#undef MM16
#undef PAIR

    BAR;  // all waves' frag reads retired before C-staging reuses SH

    // ---- epilogue: acc C/D layout col = lane&15, row = quad*4 + reg [m89/m91].
    // Stage into LDS (group-XOR ^quad -> conflict-free writes; full-row reads),
    // then fully-coalesced global stores (R2-verified: WRITE_SIZE == logical).
    const long long cb = (long long)bz * sC + (long long)kIdx * sK;
    if (OUT_BF16) {
        ushort* Cb = (ushort*)Cp;
        // stage: SH as [256 rows][16 groups of 16 ushorts], group ^= quad
#pragma unroll
        for (int j = 0; j < 4; j++) {
            const int cg = wn * 4 + j;  // col group (col>>4), uniform per wave
            const float bv = HAS_BIAS ? bias[tn * 256 + cg * 16 + l16] : 0.0f;
#pragma unroll
            for (int i = 0; i < 8; i++) {
                const int rbase = wm * 128 + i * 16 + quad * 4;
#pragma unroll
                for (int r = 0; r < 4; r++) {
                    const int row = rbase + r;
                    float v = acc[i][j][r] * scale + bv;
                    if (RELU) v = v > 0.f ? v : 0.f;
                    SH[row * 256 + ((cg ^ ((row >> 2) & 3)) << 4) + l16] = f2b(v);
                }
            }
        }
        BAR;
        // readout: 16 passes x (16 rows x 32 chunks of 16B); 512B contiguous/row
        const int crow = tid >> 5;  // 0..15
        const int cch = tid & 31;   // 0..31
        const int g = cch >> 1, hh = cch & 1;
#pragma unroll
        for (int pass = 0; pass < 16; pass++) {
            const int row = pass * 16 + crow;
            s16x8 vv = *(const s16x8*)&SH[row * 256 + ((g ^ ((row >> 2) & 3)) << 4) + hh * 8];
            *(s16x8*)&Cb[cb + (long long)(tm * 256 + row) * ldc + tn * 256 + cch * 8] = vv;
        }
    } else {
        float* Cf = (float*)Cp;
        float* SHf = (float*)SH;  // [128 rows][32 groups of 8 floats] per half-pass
#pragma unroll
        for (int half = 0; half < 2; half++) {
            if (wm == half) {
#pragma unroll
                for (int j = 0; j < 4; j++) {
                    const int col = wn * 64 + j * 16 + l16;
                    const float bv = (HAS_BIAS && kIdx == 0) ? bias[tn * 256 + col] : 0.0f;
                    const int gg = col >> 3, cl = col & 7;
#pragma unroll
                    for (int i = 0; i < 8; i++) {
                        const int rbase = i * 16 + quad * 4;  // row within half
#pragma unroll
                        for (int r = 0; r < 4; r++) {
                            const int row = rbase + r;
                            float v = acc[i][j][r] * scale + bv;
                            if (RELU) v = v > 0.f ? v : 0.f;
                            SHf[row * 256 + ((gg ^ ((row >> 2) & 3)) << 3) + cl] = v;
                        }
                    }
                }
            }
            BAR;
            // readout: 16 passes x (8 rows x 64 chunks of 16B); 1024B contiguous/row
            const int rr = tid >> 6, cc = tid & 63;
            const int g2 = cc >> 1, h2 = cc & 1;
#pragma unroll
            for (int pass = 0; pass < 16; pass++) {
                const int row = pass * 8 + rr;
                f32x4 vv = *(const f32x4*)&SHf[row * 256 + ((g2 ^ ((row >> 2) & 3)) << 3) + h2 * 4];
                *(f32x4*)&Cf[cb + (long long)(tm * 256 + half * 128 + row) * ldc + tn * 256 + cc * 4] = vv;
            }
            BAR;
        }
    }
#undef BAR
#undef PRIO1
#undef PRIO0
#undef WVM4
#undef WVM0
#undef WLG0
}

// ---------------- row softmax: bf16 [rows][2048] -> bf16, vectorized 8/thread -------

__global__ __launch_bounds__(256) void softmax_rows(const ushort* __restrict__ S,
                                                    ushort* __restrict__ P) {
    const int C = 2048;
    const long long row = blockIdx.x;
    const int tid = threadIdx.x;
    const ushort4* s4 = (const ushort4*)(S + row * C) + tid * 2;  // 8 contiguous elems
    ushort4 a = s4[0], bq = s4[1];
    float v[8];
    v[0] = b2f(a.x); v[1] = b2f(a.y); v[2] = b2f(a.z); v[3] = b2f(a.w);
    v[4] = b2f(bq.x); v[5] = b2f(bq.y); v[6] = b2f(bq.z); v[7] = b2f(bq.w);
    float mx = -1e30f;
#pragma unroll
    for (int i = 0; i < 8; i++) mx = fmaxf(mx, v[i]);
    __shared__ float red[256];
    red[tid] = mx;
    __syncthreads();
    for (int off = 128; off > 0; off >>= 1) {
        if (tid < off) red[tid] = fmaxf(red[tid], red[tid + off]);
        __syncthreads();
    }
    mx = red[0];
    __syncthreads();
    float sum = 0.f;
#pragma unroll
    for (int i = 0; i < 8; i++) {
        v[i] = __expf(v[i] - mx);
        sum += v[i];
    }
    red[tid] = sum;
    __syncthreads();
    for (int off = 128; off > 0; off >>= 1) {
        if (tid < off) red[tid] += red[tid + off];
        __syncthreads();
    }
    float inv = 1.f / red[0];
    ushort4 o0, o1;
    o0.x = f2b(v[0] * inv); o0.y = f2b(v[1] * inv); o0.z = f2b(v[2] * inv); o0.w = f2b(v[3] * inv);
    o1.x = f2b(v[4] * inv); o1.y = f2b(v[5] * inv); o1.z = f2b(v[6] * inv); o1.w = f2b(v[7] * inv);
    ushort4* p4 = (ushort4*)(P + row * C) + tid * 2;
    p4[0] = o0;
    p4[1] = o1;
}

// ---------------- fused residual(+partial-sum) + LayerNorm (D=1024) ----------------
// out = LN(X + Y + (Y2?)) ; Y2 nullable (split-K partial reduction fused here).

__global__ __launch_bounds__(256) void residual_ln(const float* __restrict__ X,
                                                   const float* __restrict__ Y,
                                                   const float* __restrict__ Y2,
                                                   const float* __restrict__ g,
                                                   const float* __restrict__ be,
                                                   float* __restrict__ outf,
                                                   ushort* __restrict__ outb) {
    const int D = 1024;
    const long long row = blockIdx.x;
    const float* x = X + row * D;
    const float* y = Y + row * D;
    const float* y2 = Y2 ? Y2 + row * D : nullptr;
    const int tid = threadIdx.x;
    float v[4];
    float s = 0.f, s2 = 0.f;
#pragma unroll
    for (int i = 0; i < 4; i++) {
        int c = tid + i * 256;
        float t = x[c] + y[c];
        if (y2) t += y2[c];
        v[i] = t;
        s += t;
        s2 += t * t;
    }
    __shared__ float r1[256], r2[256];
    r1[tid] = s;
    r2[tid] = s2;
    __syncthreads();
    for (int off = 128; off > 0; off >>= 1) {
        if (tid < off) {
            r1[tid] += r1[tid + off];
            r2[tid] += r2[tid + off];
        }
        __syncthreads();
    }
    float mu = r1[0] * (1.f / 1024.f);
    float var = r2[0] * (1.f / 1024.f) - mu * mu;
    float inv = rsqrtf(var + 1e-5f);
    float* of = outf + row * D;
    ushort* ob = outb ? outb + row * D : nullptr;
#pragma unroll
    for (int i = 0; i < 4; i++) {
        int c = tid + i * 256;
        float o = (v[i] - mu) * inv * g[c] + be[c];
        of[c] = o;
        if (ob) ob[c] = f2b(o);
    }
}

// ---------------- launch ----------------

extern "C" void kernel_launch(void* const* d_in, const int* in_sizes, int n_in,
                              void* d_out, int out_size, void* d_ws, size_t ws_size,
                              hipStream_t stream) {
    const float* x  = (const float*)d_in[0];
    const float* wq = (const float*)d_in[1];
    const float* bq = (const float*)d_in[2];
    const float* wk = (const float*)d_in[3];
    const float* bk = (const float*)d_in[4];
    const float* wv = (const float*)d_in[5];
    const float* bv = (const float*)d_in[6];
    const float* wo = (const float*)d_in[7];
    const float* bo = (const float*)d_in[8];
    const float* w1 = (const float*)d_in[9];
    const float* b1 = (const float*)d_in[10];
    const float* w2 = (const float*)d_in[11];
    const float* b2 = (const float*)d_in[12];
    const float* g1 = (const float*)d_in[13];
    const float* be1 = (const float*)d_in[14];
    const float* g2 = (const float*)d_in[15];
    const float* be2 = (const float*)d_in[16];
    float* out = (float*)d_out;
    char* ws = (char*)d_ws;

    const int Bz = 4, S = 2048, D = 1024, F = 4096;
    const int T = Bz * S;  // 8192 rows
    const size_t MBy = 1024ull * 1024ull;

    // workspace layout (byte offsets), lifetime-based reuse; peak 201 MB
    ushort* qkvT = (ushort*)(ws + 0);        // 6 MB  [3072][1024]; woT follows contiguously
    ushort* woT  = (ushort*)(ws + 6 * MBy);  // 2 MB
    ushort* w1T  = (ushort*)(ws + 8 * MBy);  // 8 MB   [F][D]
    ushort* w2T  = (ushort*)(ws + 16 * MBy); // 8 MB   [D][F]
    float*  bqkv = (float*)(ws + 24 * MBy);  // 12 KB  (dead after QKV gemm)
    ushort* xb   = (ushort*)(ws + 25 * MBy); // 16 MB  (dead after QKV gemm)
    ushort* qkv  = (ushort*)(ws + 41 * MBy); // 48 MB  [T][3072] (dead after scores+vT)
    ushort* vT   = (ushort*)(ws + 89 * MBy); // 16 MB  [B][D][S] (dead after ctx)
    ushort* scb  = (ushort*)(ws + 105 * MBy); // 32 MB bf16 scores (dead after softmax)
    ushort* attn = (ushort*)(ws + 169 * MBy); // 32 MB (dead after ctx)
    // reuse (non-overlapping lifetimes):
    float*  ctx0 = (float*)(ws + 105 * MBy); // 32 MB over scb (dead after add2_cast)
    float*  ctx1 = (float*)(ws + 137 * MBy); // 32 MB (dead after add2_cast)
    ushort* ctxb = (ushort*)(ws + 25 * MBy); // 16 MB over xb (dead after wo)
    float*  ao0 = (float*)(ws + 105 * MBy);  // 32 MB over ctx0 (dead after ln1)
    float*  ao1 = (float*)(ws + 137 * MBy);  // 32 MB (dead after ln1)
    float*  x1  = (float*)(ws + 41 * MBy);   // 32 MB over qkv (live to ln2)
    ushort* x1b = (ushort*)(ws + 73 * MBy);  // 16 MB over qkv (dead after ffn1)
    ushort* h   = (ushort*)(ws + 105 * MBy); // 64 MB over ao (after ln1)
    float*  ff0 = (float*)(ws + 169 * MBy);  // 32 MB over attn
    float*  ff1 = (float*)(ws + 73 * MBy);   // 32 MB over x1b+vT (both dead by ffn2)

    dim3 b32(32, 8);

    // 1) cast x -> bf16
    cast_f2b4<<<(T * D) / 1024, 256, 0, stream>>>(x, xb, (long long)(T * D) / 4);

    // 2) transpose-cast weights: wq/wk/wv/wo -> [qkvT|woT] in ONE dispatch; w1, w2
    transpose4_to_bf16<<<dim3(32, 32, 4), b32, 0, stream>>>(wq, wk, wv, wo, qkvT);
    transpose_to_bf16<float><<<dim3(128, 32, 1), b32, 0, stream>>>(w1, w1T, D, F, F, 0, 0);
    transpose_to_bf16<float><<<dim3(32, 128, 1), b32, 0, stream>>>(w2, w2T, F, D, D, 0, 0);

    // 3) fused bias vector [bq|bk|bv]
    concat3<<<12, 256, 0, stream>>>(bq, bk, bv, bqkv);

    // 4) fused QKV projection: [T][1024] x [3072][1024]^T -> [T][3072] bf16 (384 blocks)
    gemm256<1, 0, 1><<<dim3(3 * D / 256, T / 256, 1), 512, 0, stream>>>(
        xb, qkvT, qkv, bqkv, D, 1, 1.f, D, D, 3 * D, 0, 0, 0, 0);

    // 5) V^T per batch: qkv v-slice [S][1024] (ld 3072) -> [D][S]
    transpose_to_bf16<ushort><<<dim3(D / 32, S / 32, Bz), b32, 0, stream>>>(
        qkv + 2048, vT, S, D, 3 * D, (long long)S * 3 * D, (long long)S * D);

    // 6) scores = Q K^T / 32 -> bf16; A=q, B=k slices of qkv (ld 3072) (256 blocks)
    gemm256<1, 0, 0><<<dim3(S / 256, S / 256, Bz), 512, 0, stream>>>(
        qkv, qkv + 1024, scb, nullptr, D, 1, 0.03125f, 3 * D, 3 * D, S,
        (long long)S * 3 * D, (long long)S * 3 * D, (long long)S * S, 0);

    // 7) softmax rows -> bf16 attn
    softmax_rows<<<T, 256, 0, stream>>>(scb, attn);

    // 8) ctx partials = attn @ V (BT = V^T [D][S]), split-K=2 -> fp32 (256 blocks)
    gemm256<0, 0, 0><<<dim3(D / 256, S / 256, Bz * 2), 512, 0, stream>>>(
        attn, vT, ctx0, nullptr, S, 2, 1.f, S, S, D,
        (long long)S * S, (long long)D * S, (long long)S * D, (long long)(ctx1 - ctx0));

    // 8b) ctx = ctx0 + ctx1 -> bf16
    add2_cast<<<(T * D) / 1024, 256, 0, stream>>>(ctx0, ctx1, ctxb, (long long)(T * D) / 4);

    // 9) attn_out partials = ctx @ wo^T (+bo chunk 0), split-K=2 (256 blocks)
    gemm256<0, 0, 1><<<dim3(D / 256, T / 256, 2), 512, 0, stream>>>(
        ctxb, woT, ao0, bo, D, 2, 1.f, D, D, D, 0, 0, 0, (long long)(ao1 - ao0));

    // 10) x1 = LN(x + ao0 + ao1) -> fp32 + bf16 (split-K reduction fused)
    residual_ln<<<T, 256, 0, stream>>>(x, ao0, ao1, g1, be1, x1, x1b);

    // 11) h = relu(x1 @ w1 + b1) (bf16, 512 blocks)
    gemm256<1, 1, 1><<<dim3(F / 256, T / 256, 1), 512, 0, stream>>>(
        x1b, w1T, h, b1, D, 1, 1.f, D, D, F, 0, 0, 0, 0);

    // 12) ff partials = h @ w2 (+b2 on chunk 0), split-K=2 (256 blocks)
    gemm256<0, 0, 1><<<dim3(D / 256, T / 256, 2), 512, 0, stream>>>(
        h, w2T, ff0, b2, F, 2, 1.f, F, F, D, 0, 0, 0, (long long)(ff1 - ff0));

    // 13) out = LN(x1 + ff0 + ff1) -> d_out fp32 (split-K reduction fused)
    residual_ln<<<T, 256, 0, stream>>>(x1, ff0, ff1, g2, be2, out, nullptr);
}